// Round 2
// baseline (10216.728 us; speedup 1.0000x reference)
//
#include <hip/hip_runtime.h>
#include <hip/hip_cooperative_groups.h>
#include <math.h>

namespace cg = cooperative_groups;

// Round 11: FUSE sequential steps into cooperative kernels.
// r10 post-mortem: regrid 128->256 blocks was neutral (-74us) -> steps are
// launch-overhead-bound (~20us/launch x 200 launches ~= the whole 4.4ms),
// not CU-limited. Fix: enc_all = 128 steps in ONE cooperative kernel
// (grid.sync between steps, Whh frag LDS-resident 64KB, c-state in regs);
// dec_all = 24 steps x {qk-gemm, attn, lstm} in ONE cooperative kernel
// (3 grid syncs/step, Wdh LDS-resident). 256 blocks x 512 thr, ~85KB LDS
// -> 1 block/CU, co-residency guaranteed. Math identical to r10.

#define NB 128
#define NL 128
#define NH 1024
#define NA 256
#define NT 24
#define NM 151

typedef __attribute__((ext_vector_type(8))) short bf16x8;
typedef __attribute__((ext_vector_type(8))) short s16x8;
typedef __attribute__((ext_vector_type(4))) float f32x4;

#define MFMA(a, b, acc) __builtin_amdgcn_mfma_f32_16x16x32_bf16(a, b, acc, 0, 0, 0)

#define I16_SCALE 32767.0f
#define I16_INV   (1.0f / 32767.0f)

__device__ __forceinline__ float sig_f(float x) {
  return 1.0f / (1.0f + __expf(-x));
}
__device__ __forceinline__ float tanh_f(float x) {
  x = fminf(9.0f, fmaxf(-9.0f, x));
  float e = __expf(2.0f * x);
  return (e - 1.0f) / (e + 1.0f);
}
__device__ __forceinline__ unsigned short f2bf(float f) {
  unsigned int u = __float_as_uint(f);
  u = (u + 0x7FFFu + ((u >> 16) & 1u)) >> 16;
  return (unsigned short)u;
}
__device__ __forceinline__ float bf2f(unsigned short u) {
  return __uint_as_float(((unsigned int)u) << 16);
}
__device__ __forceinline__ short f2i16(float f) {
  return (short)__float2int_rn(f * I16_SCALE);
}

// ---------------------------------------------------------------------------
// conv front (proven round 1)
// ---------------------------------------------------------------------------
__global__ __launch_bounds__(128) void conv_front(
    const float* __restrict__ x,
    const float* __restrict__ w1, const float* __restrict__ b1,
    const float* __restrict__ w2, const float* __restrict__ b2,
    const float* __restrict__ w3, const float* __restrict__ b3,
    float* __restrict__ lstm_in)
{
  int b = blockIdx.x;
  int t = threadIdx.x;
  __shared__ float d[128][36];
  __shared__ float h1[128][34];
  __shared__ float h2[128][32];

  const float* xr = x + (size_t)(b * NL + t) * 48;
  #pragma unroll
  for (int f = 0; f < 36; ++f) d[t][f] = xr[f];
  __syncthreads();

  float acc[34];
  {
    float bias = b1[t];
    #pragma unroll
    for (int w = 0; w < 34; ++w) acc[w] = bias;
  }
  const float* wr = w1 + t * 384;
  for (int ci = 0; ci < 128; ++ci) {
    float row[36];
    #pragma unroll
    for (int f = 0; f < 36; ++f) row[f] = d[ci][f];
    float wa = wr[ci * 3 + 0], wb = wr[ci * 3 + 1], wc = wr[ci * 3 + 2];
    #pragma unroll
    for (int w = 0; w < 34; ++w)
      acc[w] += row[w] * wa + row[w + 1] * wb + row[w + 2] * wc;
  }
  #pragma unroll
  for (int w = 0; w < 34; ++w) {
    float z = acc[w];
    h1[t][w] = (z > 20.0f) ? z : log1pf(__expf(z));
  }
  __syncthreads();

  float acc2[32];
  {
    float bias = b2[t];
    #pragma unroll
    for (int w = 0; w < 32; ++w) acc2[w] = bias;
  }
  const float* wr2 = w2 + t * 384;
  for (int ci = 0; ci < 128; ++ci) {
    float row[34];
    #pragma unroll
    for (int f = 0; f < 34; ++f) row[f] = h1[ci][f];
    float wa = wr2[ci * 3 + 0], wb = wr2[ci * 3 + 1], wc = wr2[ci * 3 + 2];
    #pragma unroll
    for (int w = 0; w < 32; ++w)
      acc2[w] += row[w] * wa + row[w + 1] * wb + row[w + 2] * wc;
  }
  #pragma unroll
  for (int w = 0; w < 32; ++w) h2[t][w] = fmaxf(acc2[w], 0.0f);
  __syncthreads();

  float* outr = lstm_in + (size_t)(b * NL + t) * 18;
  #pragma unroll
  for (int e = 0; e < 6; ++e) {
    float s = b3[e];
    #pragma unroll
    for (int f = 0; f < 32; ++f) s += h2[t][f] * w3[e * 32 + f];
    outr[e] = s;
  }
  #pragma unroll
  for (int j = 0; j < 12; ++j) outr[6 + j] = xr[36 + j];
}

// ---------------------------------------------------------------------------
// Fragment-order transforms (4-column variant, as round 10).
// ---------------------------------------------------------------------------
__global__ void frag_w4(const float* __restrict__ src, int K, int kshift,
                        unsigned short* __restrict__ hi,
                        unsigned short* __restrict__ lo, int ngroups)
{
  int o = blockIdx.x * 256 + threadIdx.x;
  if (o >= ngroups) return;
  int lane = o & 63;
  int ki = (o >> 6) & ((1 << kshift) - 1);
  int t2 = o >> (6 + kshift);
  int l15 = lane & 15, q = lane >> 4;
  int grow = (l15 >> 2) * 1024 + t2 * 4 + (l15 & 3);
  const float* s = src + (size_t)grow * K + ki * 32 + q * 8;
  unsigned short hv[8], lv[8];
  #pragma unroll
  for (int j = 0; j < 8; ++j) {
    float v = s[j];
    hv[j] = f2bf(v);
    lv[j] = f2bf(v - bf2f(hv[j]));
  }
  size_t e = (size_t)o * 8;
  *(ushort4*)(hi + e) = make_ushort4(hv[0], hv[1], hv[2], hv[3]);
  *(ushort4*)(hi + e + 4) = make_ushort4(hv[4], hv[5], hv[6], hv[7]);
  *(ushort4*)(lo + e) = make_ushort4(lv[0], lv[1], lv[2], lv[3]);
  *(ushort4*)(lo + e + 4) = make_ushort4(lv[4], lv[5], lv[6], lv[7]);
}

__global__ void frag_wqk(const float* __restrict__ wq,
                         const float* __restrict__ wk,
                         unsigned short* __restrict__ hi,
                         unsigned short* __restrict__ lo)
{
  int o = blockIdx.x * 256 + threadIdx.x;
  if (o >= 65536) return;
  int lane = o & 63;
  int ki = (o >> 6) & 31;
  int ntile = o >> 11;
  int l15 = lane & 15, q = lane >> 4;
  int row = ntile * 16 + l15;
  int k = ki * 32 + q * 8;
  const float* s = (row < 256) ? (wq + (size_t)row * 1024 + k)
                               : (wk + (size_t)(row - 256) * 1024 + k);
  unsigned short hv[8], lv[8];
  #pragma unroll
  for (int j = 0; j < 8; ++j) {
    float v = s[j];
    hv[j] = f2bf(v);
    lv[j] = f2bf(v - bf2f(hv[j]));
  }
  size_t e = (size_t)o * 8;
  *(ushort4*)(hi + e) = make_ushort4(hv[0], hv[1], hv[2], hv[3]);
  *(ushort4*)(hi + e + 4) = make_ushort4(hv[4], hv[5], hv[6], hv[7]);
  *(ushort4*)(lo + e) = make_ushort4(lv[0], lv[1], lv[2], lv[3]);
  *(ushort4*)(lo + e + 4) = make_ushort4(lv[4], lv[5], lv[6], lv[7]);
}

__global__ void frag_wx4(const float* __restrict__ wih,
                         unsigned short* __restrict__ hi,
                         unsigned short* __restrict__ lo)
{
  int o = blockIdx.x * 256 + threadIdx.x;
  if (o >= 16384) return;
  int lane = o & 63;
  int t2 = o >> 6;
  int l15 = lane & 15, q = lane >> 4;
  int grow = (l15 >> 2) * 1024 + t2 * 4 + (l15 & 3);
  unsigned short hv[8], lv[8];
  #pragma unroll
  for (int j = 0; j < 8; ++j) {
    int k = q * 8 + j;
    float v = (k < 18) ? wih[(size_t)grow * 18 + k] : 0.0f;
    hv[j] = f2bf(v);
    lv[j] = f2bf(v - bf2f(hv[j]));
  }
  size_t e = (size_t)o * 8;
  *(ushort4*)(hi + e) = make_ushort4(hv[0], hv[1], hv[2], hv[3]);
  *(ushort4*)(hi + e + 4) = make_ushort4(hv[4], hv[5], hv[6], hv[7]);
  *(ushort4*)(lo + e) = make_ushort4(lv[0], lv[1], lv[2], lv[3]);
  *(ushort4*)(lo + e + 4) = make_ushort4(lv[4], lv[5], lv[6], lv[7]);
}

__global__ void frag_xs(const float* __restrict__ lstm_in,
                        unsigned short* __restrict__ hi,
                        unsigned short* __restrict__ lo)
{
  int o = blockIdx.x * 256 + threadIdx.x;
  if (o >= 65536) return;
  int lane = o & 63;
  int btile = (o >> 6) & 7;
  int t = o >> 9;
  int l15 = lane & 15, q = lane >> 4;
  int b = btile * 16 + l15;
  unsigned short hv[8], lv[8];
  #pragma unroll
  for (int j = 0; j < 8; ++j) {
    int k = q * 8 + j;
    float v = (k < 18) ? lstm_in[(size_t)(b * NL + t) * 18 + k] : 0.0f;
    hv[j] = f2bf(v);
    lv[j] = f2bf(v - bf2f(hv[j]));
  }
  size_t e = (size_t)o * 8;
  *(ushort4*)(hi + e) = make_ushort4(hv[0], hv[1], hv[2], hv[3]);
  *(ushort4*)(hi + e + 4) = make_ushort4(hv[4], hv[5], hv[6], hv[7]);
  *(ushort4*)(lo + e) = make_ushort4(lv[0], lv[1], lv[2], lv[3]);
  *(ushort4*)(lo + e + 4) = make_ushort4(lv[4], lv[5], lv[6], lv[7]);
}

__global__ void init_all(float* __restrict__ c,
                         unsigned short* __restrict__ hhi0,
                         unsigned short* __restrict__ hlo0,
                         float* __restrict__ out) {
  int i = blockIdx.x * 256 + threadIdx.x;
  if (i < NB * NH) { c[i] = 0.0f; hhi0[i] = 0; hlo0[i] = 0; }
  if (i < NB * NT) out[i] = 0.0f;
}

// ---------------------------------------------------------------------------
// enc_all: all 128 encoder steps in one cooperative kernel.
// 256 blocks x 512 thr, block owns 4 gate-columns. Whh frag slice (64KB)
// LDS-resident; c-state in registers; grid.sync between steps.
// ---------------------------------------------------------------------------
__global__ __launch_bounds__(512) void enc_all(
    unsigned short* __restrict__ hfA_hi, unsigned short* __restrict__ hfA_lo,
    unsigned short* __restrict__ hfB_hi, unsigned short* __restrict__ hfB_lo,
    const unsigned short* __restrict__ Wf_hi,
    const unsigned short* __restrict__ Wf_lo,
    const unsigned short* __restrict__ Wxf_hi,
    const unsigned short* __restrict__ Wxf_lo,
    const unsigned short* __restrict__ xsf_hi,
    const unsigned short* __restrict__ xsf_lo,
    const float* __restrict__ encb,
    float* __restrict__ c,
    short* __restrict__ buf)
{
  cg::grid_group grid = cg::this_grid();
  __shared__ __align__(16) unsigned short SWh[16384];
  __shared__ __align__(16) unsigned short SWl[16384];
  __shared__ __align__(16) unsigned short SXh[512];
  __shared__ __align__(16) unsigned short SXl[512];
  __shared__ float G[2][128][17];

  int tid = threadIdx.x;
  int bx = blockIdx.x;
  int w8 = tid >> 6, lane = tid & 63;
  int grp = w8 >> 2, wm = w8 & 3;
  int l15 = lane & 15, q4 = (lane >> 4) * 4;
  int kc = bx * 4;

  {
    const unsigned short* gh = Wf_hi + (size_t)bx * 16384;
    const unsigned short* gl = Wf_lo + (size_t)bx * 16384;
    for (int i = tid * 8; i < 16384; i += 4096) {
      *(bf16x8*)(SWh + i) = *(const bf16x8*)(gh + i);
      *(bf16x8*)(SWl + i) = *(const bf16x8*)(gl + i);
    }
    if (tid < 64) {
      *(bf16x8*)(SXh + tid * 8) =
          *(const bf16x8*)(Wxf_hi + (size_t)bx * 512 + tid * 8);
      *(bf16x8*)(SXl + tid * 8) =
          *(const bf16x8*)(Wxf_lo + (size_t)bx * 512 + tid * 8);
    }
  }

  float bias[4][4];
  float4 creg = make_float4(0.f, 0.f, 0.f, 0.f);
  if (tid < 128) {
    #pragma unroll
    for (int q = 0; q < 4; ++q)
      #pragma unroll
      for (int j = 0; j < 4; ++j)
        bias[q][j] = encb[q * NH + kc + j];
  }
  __syncthreads();

  for (int t = 0; t < NL; ++t) {
    const unsigned short* hih = (t & 1) ? hfB_hi : hfA_hi;
    const unsigned short* hil = (t & 1) ? hfB_lo : hfA_lo;
    unsigned short* hoh = (t & 1) ? hfA_hi : hfB_hi;
    unsigned short* hol = (t & 1) ? hfA_lo : hfB_lo;

    const unsigned short* A0h = hih + (size_t)(2 * wm) * 512 + lane * 8;
    const unsigned short* A1h = hih + (size_t)(2 * wm + 1) * 512 + lane * 8;
    const unsigned short* A0l = hil + (size_t)(2 * wm) * 512 + lane * 8;
    const unsigned short* A1l = hil + (size_t)(2 * wm + 1) * 512 + lane * 8;
    const unsigned short* SBh = SWh + lane * 8;
    const unsigned short* SBl = SWl + lane * 8;

    f32x4 a00 = {0,0,0,0}, a10 = {0,0,0,0};
    for (int i = 0; i < 16; ++i) {
      int ki = grp * 16 + i;
      size_t ao = (size_t)ki * 4096;
      int bo = ki * 512;
      bf16x8 x0h = *(const bf16x8*)(A0h + ao);
      bf16x8 x0l = *(const bf16x8*)(A0l + ao);
      bf16x8 x1h = *(const bf16x8*)(A1h + ao);
      bf16x8 x1l = *(const bf16x8*)(A1l + ao);
      bf16x8 yh = *(const bf16x8*)(SBh + bo);
      bf16x8 yl = *(const bf16x8*)(SBl + bo);
      a00 = MFMA(x0h, yh, a00); a00 = MFMA(x0l, yh, a00); a00 = MFMA(x0h, yl, a00);
      a10 = MFMA(x1h, yh, a10); a10 = MFMA(x1l, yh, a10); a10 = MFMA(x1h, yl, a10);
    }
    if (grp == 0) {
      size_t xo0 = ((size_t)t * 8 + 2 * wm) * 512 + lane * 8;
      size_t xo1 = xo0 + 512;
      bf16x8 x0h = *(const bf16x8*)(xsf_hi + xo0);
      bf16x8 x0l = *(const bf16x8*)(xsf_lo + xo0);
      bf16x8 x1h = *(const bf16x8*)(xsf_hi + xo1);
      bf16x8 x1l = *(const bf16x8*)(xsf_lo + xo1);
      bf16x8 yh = *(const bf16x8*)(SXh + lane * 8);
      bf16x8 yl = *(const bf16x8*)(SXl + lane * 8);
      a00 = MFMA(x0h, yh, a00); a00 = MFMA(x0l, yh, a00); a00 = MFMA(x0h, yl, a00);
      a10 = MFMA(x1h, yh, a10); a10 = MFMA(x1l, yh, a10); a10 = MFMA(x1h, yl, a10);
    }
    #pragma unroll
    for (int r = 0; r < 4; ++r) {
      G[grp][32 * wm + q4 + r][l15]      = a00[r];
      G[grp][32 * wm + 16 + q4 + r][l15] = a10[r];
    }
    __syncthreads();

    if (tid < 128) {
      int b = tid;
      float rh[4];
      float* cp = &creg.x;
      #pragma unroll
      for (int j = 0; j < 4; ++j) {
        float gate[4];
        #pragma unroll
        for (int q = 0; q < 4; ++q)
          gate[q] = G[0][b][q * 4 + j] + G[1][b][q * 4 + j] + bias[q][j];
        float cn = sig_f(gate[1]) * cp[j] + sig_f(gate[0]) * tanh_f(gate[2]);
        float hn = sig_f(gate[3]) * tanh_f(cn);
        cp[j] = cn; rh[j] = hn;
      }
      unsigned short hh[4], hl[4];
      short hq[4];
      #pragma unroll
      for (int j = 0; j < 4; ++j) {
        hh[j] = f2bf(rh[j]);
        hl[j] = f2bf(rh[j] - bf2f(hh[j]));
        hq[j] = f2i16(rh[j]);
      }
      int ki = kc >> 5, qq = (kc >> 3) & 3, j8 = kc & 7;
      size_t fo = (size_t)ki * 4096 + (b >> 4) * 512 + ((b & 15) + 16 * qq) * 8 + j8;
      *(ushort4*)(hoh + fo) = make_ushort4(hh[0], hh[1], hh[2], hh[3]);
      *(ushort4*)(hol + fo) = make_ushort4(hl[0], hl[1], hl[2], hl[3]);
      *(short4*)(buf + (size_t)(b * NM + t) * NH + kc) =
          make_short4(hq[0], hq[1], hq[2], hq[3]);
    }
    grid.sync();
  }
  if (tid < 128)
    *(float4*)(c + (size_t)tid * NH + kc) = creg;
}

// ---------------------------------------------------------------------------
// dec_prep: read final h (frag) + c (row-major) -> q frag rows 2b / 2b+1.
// ---------------------------------------------------------------------------
__global__ __launch_bounds__(256) void dec_prep(
    const unsigned short* __restrict__ hf_hi,
    const unsigned short* __restrict__ hf_lo,
    const float* __restrict__ c,
    unsigned short* __restrict__ qhi, unsigned short* __restrict__ qlo)
{
  int b = blockIdx.x;
  int j4 = threadIdx.x * 4;
  int ki = j4 >> 5, qq = (j4 >> 3) & 3, j8 = j4 & 7;
  size_t fh = (size_t)ki * 4096 + (b >> 4) * 512 + ((b & 15) + 16 * qq) * 8 + j8;
  ushort4 hv = *(const ushort4*)(hf_hi + fh);
  ushort4 lv = *(const ushort4*)(hf_lo + fh);
  float4 cv = *(const float4*)(c + (size_t)b * NH + j4);
  unsigned short ch[4], cl[4];
  float cf[4] = {cv.x, cv.y, cv.z, cv.w};
  #pragma unroll
  for (int k = 0; k < 4; ++k) {
    ch[k] = f2bf(cf[k]); cl[k] = f2bf(cf[k] - bf2f(ch[k]));
  }
  int rt = (2 * b) >> 4;
  int rl = ((2 * b) & 15) + 16 * qq;
  size_t fq = (size_t)ki * 8192 + rt * 512 + rl * 8 + j8;
  *(ushort4*)(qhi + fq) = hv;
  *(ushort4*)(qlo + fq) = lv;
  *(ushort4*)(qhi + fq + 8) = make_ushort4(ch[0], ch[1], ch[2], ch[3]);
  *(ushort4*)(qlo + fq + 8) = make_ushort4(cl[0], cl[1], cl[2], cl[3]);
}

// ---------------------------------------------------------------------------
// Bulk kp: kp = buf(i16, row-major) @ Wk^T (frag B, 2-term). grid(302,4).
// ---------------------------------------------------------------------------
__global__ __launch_bounds__(256) void gemm_kp(
    const short* __restrict__ A,
    const unsigned short* __restrict__ Bhi,
    const unsigned short* __restrict__ Blo,
    unsigned short* __restrict__ C)
{
  int tid = threadIdx.x;
  int w = tid >> 6, lane = tid & 63;
  int l15 = lane & 15, q8 = (lane >> 4) * 8, q4 = (lane >> 4) * 4;
  size_t m0 = (size_t)blockIdx.x * 64;
  int n0 = blockIdx.y * 64 + w * 16;
  int ntile = 16 + blockIdx.y * 4 + w;

  const unsigned short* Bh = Bhi + (size_t)ntile * 16384 + lane * 8;
  const unsigned short* Bl = Blo + (size_t)ntile * 16384 + lane * 8;
  f32x4 acc[4] = {{0,0,0,0},{0,0,0,0},{0,0,0,0},{0,0,0,0}};
  for (int ki = 0; ki < 32; ++ki) {
    int ko = ki * 32 + q8;
    size_t bo = (size_t)ki * 512;
    bf16x8 bh = *(const bf16x8*)(Bh + bo);
    bf16x8 bl = *(const bf16x8*)(Bl + bo);
    #pragma unroll
    for (int i = 0; i < 4; ++i) {
      s16x8 av = *(const s16x8*)(A + (m0 + 16 * i + l15) * (size_t)NH + ko);
      bf16x8 ah;
      #pragma unroll
      for (int k = 0; k < 8; ++k)
        ah[k] = (short)f2bf((float)av[k] * I16_INV);
      acc[i] = MFMA(ah, bh, acc[i]);
      acc[i] = MFMA(ah, bl, acc[i]);
    }
  }
  #pragma unroll
  for (int i = 0; i < 4; ++i)
    #pragma unroll
    for (int r = 0; r < 4; ++r)
      C[(m0 + 16 * i + q4 + r) * NA + n0 + l15] = f2bf(acc[i][r]);
}

// ---------------------------------------------------------------------------
// dec_all: all 24 decoder steps in one cooperative kernel.
// Per step: phase1 qk-gemm (all blocks, 2 waves) -> sync -> phase2 attn
// (blocks 0..127) -> sync -> phase3 LSTM (all blocks, 4 cols, Wdh in LDS,
// c in regs) -> sync.
// ---------------------------------------------------------------------------
__global__ __launch_bounds__(512) void dec_all(
    unsigned short* __restrict__ Xf_hi, unsigned short* __restrict__ Xf_lo,
    unsigned short* __restrict__ qA_hi, unsigned short* __restrict__ qA_lo,
    unsigned short* __restrict__ qB_hi, unsigned short* __restrict__ qB_lo,
    const unsigned short* __restrict__ Wqkf_hi,
    const unsigned short* __restrict__ Wqkf_lo,
    const unsigned short* __restrict__ Wdxf_hi,
    const unsigned short* __restrict__ Wdxf_lo,
    const unsigned short* __restrict__ Wdhf_hi,
    const unsigned short* __restrict__ Wdhf_lo,
    const float* __restrict__ decb,
    const float* __restrict__ cin,
    short* __restrict__ buf,
    unsigned short* __restrict__ kp,
    float* __restrict__ qkout,
    const float* __restrict__ Wv,
    const float* __restrict__ out_w, const float* __restrict__ out_b,
    float* __restrict__ out)
{
  cg::grid_group grid = cg::this_grid();
  __shared__ __align__(16) unsigned short SDh[16384];
  __shared__ __align__(16) unsigned short SDl[16384];
  __shared__ float G[2][128][17];
  __shared__ float sWv[256], q0[256], q1[256], kNew[256];
  __shared__ float sc2[2][NM + 1];
  __shared__ float w0s[NM + 1], w1s[NM + 1];

  int tid = threadIdx.x;
  int bx = blockIdx.x;
  int w8 = tid >> 6, lane = tid & 63;
  int grp = w8 >> 2, wm = w8 & 3;
  int l15 = lane & 15, q4 = (lane >> 4) * 4;
  int kc = bx * 4;

  {
    const unsigned short* gh = Wdhf_hi + (size_t)bx * 16384;
    const unsigned short* gl = Wdhf_lo + (size_t)bx * 16384;
    for (int i = tid * 8; i < 16384; i += 4096) {
      *(bf16x8*)(SDh + i) = *(const bf16x8*)(gh + i);
      *(bf16x8*)(SDl + i) = *(const bf16x8*)(gl + i);
    }
  }
  float dbias[4][4], ow[4];
  float4 creg = make_float4(0.f, 0.f, 0.f, 0.f);
  if (tid < 128) {
    #pragma unroll
    for (int q = 0; q < 4; ++q)
      #pragma unroll
      for (int j = 0; j < 4; ++j)
        dbias[q][j] = decb[q * NH + kc + j];
    #pragma unroll
    for (int j = 0; j < 4; ++j) ow[j] = out_w[kc + j];
    creg = *(const float4*)(cin + (size_t)tid * NH + kc);
  }
  if (bx < NB && tid < 256) sWv[tid] = Wv[tid];
  __syncthreads();

  for (int t = 0; t < NT; ++t) {
    const unsigned short* qih = (t & 1) ? qB_hi : qA_hi;
    const unsigned short* qil = (t & 1) ? qB_lo : qA_lo;
    unsigned short* qoh = (t & 1) ? qA_hi : qB_hi;
    unsigned short* qol = (t & 1) ? qA_lo : qB_lo;

    // ---- phase 1: qkout = q @ Wqk^T (2 waves per block) ----
    if (w8 < 2) {
      int mtile = bx & 15;
      int ntile = (bx >> 4) * 2 + w8;
      const unsigned short* Ah = qih + (size_t)mtile * 512 + lane * 8;
      const unsigned short* Al = qil + (size_t)mtile * 512 + lane * 8;
      const unsigned short* Bh = Wqkf_hi + (size_t)ntile * 16384 + lane * 8;
      const unsigned short* Bl = Wqkf_lo + (size_t)ntile * 16384 + lane * 8;
      f32x4 acc = {0, 0, 0, 0};
      for (int ki = 0; ki < 32; ++ki) {
        size_t ao = (size_t)ki * 8192;
        size_t bo = (size_t)ki * 512;
        bf16x8 ah = *(const bf16x8*)(Ah + ao);
        bf16x8 al = *(const bf16x8*)(Al + ao);
        bf16x8 bh = *(const bf16x8*)(Bh + bo);
        bf16x8 bl = *(const bf16x8*)(Bl + bo);
        acc = MFMA(ah, bh, acc);
        acc = MFMA(al, bh, acc);
        acc = MFMA(ah, bl, acc);
      }
      #pragma unroll
      for (int r = 0; r < 4; ++r)
        qkout[(size_t)(mtile * 16 + q4 + r) * 512 + ntile * 16 + l15] = acc[r];
    }
    grid.sync();

    // ---- phase 2: attention (blocks 0..127) ----
    if (bx < NB) {
      int b = bx;
      int Mt = NL + t;
      if (tid < 256) {
        q0[tid] = qkout[(size_t)(2 * b) * 512 + tid];
        q1[tid] = qkout[(size_t)(2 * b + 1) * 512 + tid];
        float kn = qkout[(size_t)(2 * b) * 512 + 256 + tid];
        kNew[tid] = kn;
        kp[((size_t)(b * NM) + (NL - 1 + t)) * NA + tid] = f2bf(kn);
      }
      __syncthreads();
      for (int idx = tid; idx < 2 * Mt; idx += 512) {
        int m = idx >> 1, n = idx & 1;
        const float* q = n ? q1 : q0;
        float s = 0.0f;
        if (m == Mt - 1) {
          for (int a = 0; a < NA; ++a) s += tanh_f(q[a] + kNew[a]) * sWv[a];
        } else {
          const unsigned short* kpr = kp + ((size_t)(b * NM) + m) * NA;
          for (int a = 0; a < NA; a += 4) {
            ushort4 kv = *(const ushort4*)(kpr + a);
            s += tanh_f(q[a + 0] + bf2f(kv.x)) * sWv[a + 0];
            s += tanh_f(q[a + 1] + bf2f(kv.y)) * sWv[a + 1];
            s += tanh_f(q[a + 2] + bf2f(kv.z)) * sWv[a + 2];
            s += tanh_f(q[a + 3] + bf2f(kv.w)) * sWv[a + 3];
          }
        }
        sc2[n][m] = s;
      }
      __syncthreads();
      for (int m = tid; m < Mt; m += 512) {
        float s0 = sc2[0][m], s1 = sc2[1][m];
        float mx = fmaxf(s0, s1);
        float e0 = __expf(s0 - mx), e1 = __expf(s1 - mx);
        float inv = 1.0f / (e0 + e1);
        w0s[m] = e0 * inv;
        w1s[m] = e1 * inv;
      }
      __syncthreads();
      if (tid < 256) {
        float4 a0 = {0, 0, 0, 0}, a1 = {0, 0, 0, 0};
        const short* bb = buf + ((size_t)b * NM) * NH + tid * 4;
        int Mt2 = Mt;
        for (int m = 0; m < Mt2; ++m) {
          short4 v = *(const short4*)(bb + (size_t)m * NH);
          float vx = (float)v.x * I16_INV, vy = (float)v.y * I16_INV;
          float vz = (float)v.z * I16_INV, vw = (float)v.w * I16_INV;
          float w0 = w0s[m], w1 = w1s[m];
          a0.x += vx * w0; a0.y += vy * w0; a0.z += vz * w0; a0.w += vw * w0;
          a1.x += vx * w1; a1.y += vy * w1; a1.z += vz * w1; a1.w += vw * w1;
        }
        float v0[4] = {a0.x, a0.y, a0.z, a0.w};
        float v1[4] = {a1.x, a1.y, a1.z, a1.w};
        unsigned short h0[4], l0[4], h1v[4], l1v[4];
        #pragma unroll
        for (int k = 0; k < 4; ++k) {
          h0[k] = f2bf(v0[k]); l0[k] = f2bf(v0[k] - bf2f(h0[k]));
          h1v[k] = f2bf(v1[k]); l1v[k] = f2bf(v1[k] - bf2f(h1v[k]));
        }
        int k0 = tid * 4;
        size_t fo0 = (size_t)(k0 >> 5) * 4096 + (b >> 4) * 512 +
                     ((b & 15) + 16 * ((k0 >> 3) & 3)) * 8 + (k0 & 7);
        int k1 = 1024 + tid * 4;
        size_t fo1 = (size_t)(k1 >> 5) * 4096 + (b >> 4) * 512 +
                     ((b & 15) + 16 * ((k1 >> 3) & 3)) * 8 + (k1 & 7);
        *(ushort4*)(Xf_hi + fo0) = make_ushort4(h0[0], h0[1], h0[2], h0[3]);
        *(ushort4*)(Xf_lo + fo0) = make_ushort4(l0[0], l0[1], l0[2], l0[3]);
        *(ushort4*)(Xf_hi + fo1) = make_ushort4(h1v[0], h1v[1], h1v[2], h1v[3]);
        *(ushort4*)(Xf_lo + fo1) = make_ushort4(l1v[0], l1v[1], l1v[2], l1v[3]);
      }
    }
    grid.sync();

    // ---- phase 3: LSTM decoder step ----
    f32x4 a00 = {0,0,0,0}, a10 = {0,0,0,0};
    {
      const unsigned short* Wh = Wdxf_hi + (size_t)bx * 32768 + lane * 8;
      const unsigned short* Wl = Wdxf_lo + (size_t)bx * 32768 + lane * 8;
      const unsigned short* X0h = Xf_hi + (size_t)(2 * wm) * 512 + lane * 8;
      const unsigned short* X1h = Xf_hi + (size_t)(2 * wm + 1) * 512 + lane * 8;
      const unsigned short* X0l = Xf_lo + (size_t)(2 * wm) * 512 + lane * 8;
      const unsigned short* X1l = Xf_lo + (size_t)(2 * wm + 1) * 512 + lane * 8;
      int klo = grp ? 48 : 0;
      int khi = grp ? 64 : 48;
      for (int ki = klo; ki < khi; ++ki) {
        size_t ao = (size_t)ki * 4096;
        size_t bo = (size_t)ki * 512;
        bf16x8 x0h = *(const bf16x8*)(X0h + ao);
        bf16x8 x0l = *(const bf16x8*)(X0l + ao);
        bf16x8 x1h = *(const bf16x8*)(X1h + ao);
        bf16x8 x1l = *(const bf16x8*)(X1l + ao);
        bf16x8 yh = *(const bf16x8*)(Wh + bo);
        bf16x8 yl = *(const bf16x8*)(Wl + bo);
        a00 = MFMA(x0h, yh, a00); a00 = MFMA(x0l, yh, a00); a00 = MFMA(x0h, yl, a00);
        a10 = MFMA(x1h, yh, a10); a10 = MFMA(x1l, yh, a10); a10 = MFMA(x1h, yl, a10);
      }
    }
    if (grp) {
      int qt0 = 4 * wm + (l15 >> 3);
      int ln = 2 * (l15 & 7) + 16 * (lane >> 4);
      const unsigned short* A0h = qih + (size_t)qt0 * 512 + ln * 8;
      const unsigned short* A0l = qil + (size_t)qt0 * 512 + ln * 8;
      const unsigned short* A1h = qih + (size_t)(qt0 + 2) * 512 + ln * 8;
      const unsigned short* A1l = qil + (size_t)(qt0 + 2) * 512 + ln * 8;
      const unsigned short* SBh = SDh + lane * 8;
      const unsigned short* SBl = SDl + lane * 8;
      for (int ki = 0; ki < 32; ++ki) {
        size_t ao = (size_t)ki * 8192;
        int bo = ki * 512;
        bf16x8 x0h = *(const bf16x8*)(A0h + ao);
        bf16x8 x0l = *(const bf16x8*)(A0l + ao);
        bf16x8 x1h = *(const bf16x8*)(A1h + ao);
        bf16x8 x1l = *(const bf16x8*)(A1l + ao);
        bf16x8 yh = *(const bf16x8*)(SBh + bo);
        bf16x8 yl = *(const bf16x8*)(SBl + bo);
        a00 = MFMA(x0h, yh, a00); a00 = MFMA(x0l, yh, a00); a00 = MFMA(x0h, yl, a00);
        a10 = MFMA(x1h, yh, a10); a10 = MFMA(x1l, yh, a10); a10 = MFMA(x1h, yl, a10);
      }
    }
    #pragma unroll
    for (int r = 0; r < 4; ++r) {
      G[grp][32 * wm + q4 + r][l15]      = a00[r];
      G[grp][32 * wm + 16 + q4 + r][l15] = a10[r];
    }
    __syncthreads();

    if (tid < 128) {
      int b = tid;
      float rh[4], rc[4];
      float* cp = &creg.x;
      #pragma unroll
      for (int j = 0; j < 4; ++j) {
        float gate[4];
        #pragma unroll
        for (int q = 0; q < 4; ++q)
          gate[q] = G[0][b][q * 4 + j] + G[1][b][q * 4 + j] + dbias[q][j];
        float cn = sig_f(gate[1]) * cp[j] + sig_f(gate[0]) * tanh_f(gate[2]);
        float hn = sig_f(gate[3]) * tanh_f(cn);
        cp[j] = cn; rc[j] = cn; rh[j] = hn;
      }
      float py = 0.0f;
      #pragma unroll
      for (int j = 0; j < 4; ++j) py += rh[j] * ow[j];
      if (bx == 0) py += out_b[0];
      atomicAdd(&out[b * NT + t], py);

      if (t < NT - 1) {
        unsigned short hh[4], hl[4], ch[4], cl[4];
        short hq[4];
        #pragma unroll
        for (int j = 0; j < 4; ++j) {
          hh[j] = f2bf(rh[j]); hl[j] = f2bf(rh[j] - bf2f(hh[j]));
          ch[j] = f2bf(rc[j]); cl[j] = f2bf(rc[j] - bf2f(ch[j]));
          hq[j] = f2i16(rh[j]);
        }
        *(short4*)(buf + (size_t)(b * NM + NL + t) * NH + kc) =
            make_short4(hq[0], hq[1], hq[2], hq[3]);
        int ki = kc >> 5, qq = (kc >> 3) & 3, j8 = kc & 7;
        int rt = (2 * b) >> 4;
        int rl = ((2 * b) & 15) + 16 * qq;
        size_t fq = (size_t)ki * 8192 + rt * 512 + rl * 8 + j8;
        *(ushort4*)(qoh + fq) = make_ushort4(hh[0], hh[1], hh[2], hh[3]);
        *(ushort4*)(qol + fq) = make_ushort4(hl[0], hl[1], hl[2], hl[3]);
        *(ushort4*)(qoh + fq + 8) = make_ushort4(ch[0], ch[1], ch[2], ch[3]);
        *(ushort4*)(qol + fq + 8) = make_ushort4(cl[0], cl[1], cl[2], cl[3]);
      }
    }
    grid.sync();
  }
}

// ---------------------------------------------------------------------------
extern "C" void kernel_launch(void* const* d_in, const int* in_sizes, int n_in,
                              void* d_out, int out_size, void* d_ws, size_t ws_size,
                              hipStream_t stream) {
  const float* x       = (const float*)d_in[0];
  const float* conv1_w = (const float*)d_in[1];
  const float* conv1_b = (const float*)d_in[2];
  const float* conv2_w = (const float*)d_in[3];
  const float* conv2_b = (const float*)d_in[4];
  const float* lin3_w  = (const float*)d_in[5];
  const float* lin3_b  = (const float*)d_in[6];
  const float* enc_Wih = (const float*)d_in[7];
  const float* enc_Whh = (const float*)d_in[8];
  const float* enc_b   = (const float*)d_in[9];
  const float* attn_Wq = (const float*)d_in[10];
  const float* attn_Wk = (const float*)d_in[11];
  const float* attn_Wv = (const float*)d_in[12];
  const float* dec_Wih = (const float*)d_in[13];
  const float* dec_Whh = (const float*)d_in[14];
  const float* dec_b   = (const float*)d_in[15];
  const float* out_w   = (const float*)d_in[16];
  const float* out_b   = (const float*)d_in[17];
  float* out = (float*)d_out;

  // ---- workspace carve: identical totals to rounds 6-10 ----
  unsigned short* W = (unsigned short*)d_ws;
  short*          buf    = (short*)W;                  // 19,791,872 i16
  unsigned short* kp     = W + (size_t)19791872;       // 4,947,968
  unsigned short* qA_hi  = kp + 4947968;               // 262,144 (q frag)
  unsigned short* qA_lo  = qA_hi + 262144;
  unsigned short* qB_hi  = qA_lo + 262144;
  unsigned short* qB_lo  = qB_hi + 262144;
  unsigned short* Xf_hi  = qB_lo + 262144;             // 262,144 (ctx frag)
  unsigned short* Xf_lo  = Xf_hi + 262144;
  unsigned short* Wqkf_hi = Xf_lo + 262144;            // 524,288 (frag)
  unsigned short* Wqkf_lo = Wqkf_hi + 524288;
  unsigned short* Wdhf_hi = Wqkf_lo + 524288;          // 4,194,304 (enc Whh first)
  unsigned short* Wdhf_lo = Wdhf_hi + 4194304;
  unsigned short* Wdxf_hi = Wdhf_lo + 4194304;         // 8,388,608
  unsigned short* Wdxf_lo = Wdxf_hi + 8388608;         // 8,388,608
  float* c     = (float*)(Wdxf_lo + 8388608);          // 131,072 f
  float* qkout = c + 131072;                           // 131,072 f
  // encoder-phase overlays in Wdxf regions (dead until dec weight transform):
  unsigned short* hfA_hi = Wdxf_hi;                    // 131,072 (h frag)
  unsigned short* hfA_lo = Wdxf_hi + 131072;
  unsigned short* hfB_hi = Wdxf_hi + 262144;
  unsigned short* hfB_lo = Wdxf_hi + 393216;
  unsigned short* xsf_hi = Wdxf_hi + 524288;           // 524,288
  unsigned short* xsf_lo = xsf_hi + 524288;            // 524,288
  unsigned short* Wxf_hi = xsf_lo + 524288;            // 131,072
  unsigned short* Wxf_lo = Wxf_hi + 131072;            // 131,072
  float* lstm_in = (float*)Wdxf_lo;                    // 294,912 f

  init_all<<<512, 256, 0, stream>>>(c, hfA_hi, hfA_lo, out);
  conv_front<<<NB, 128, 0, stream>>>(x, conv1_w, conv1_b, conv2_w, conv2_b,
                                     lin3_w, lin3_b, lstm_in);
  frag_xs<<<256, 256, 0, stream>>>(lstm_in, xsf_hi, xsf_lo);
  frag_wx4<<<64, 256, 0, stream>>>(enc_Wih, Wxf_hi, Wxf_lo);
  frag_w4<<<2048, 256, 0, stream>>>(enc_Whh, 1024, 5, Wdhf_hi, Wdhf_lo, 524288);
  frag_wqk<<<256, 256, 0, stream>>>(attn_Wq, attn_Wk, Wqkf_hi, Wqkf_lo);

  // Encoder: 128 steps, ONE cooperative launch
  {
    void* ea[] = {
      (void*)&hfA_hi, (void*)&hfA_lo, (void*)&hfB_hi, (void*)&hfB_lo,
      (void*)&Wdhf_hi, (void*)&Wdhf_lo, (void*)&Wxf_hi, (void*)&Wxf_lo,
      (void*)&xsf_hi, (void*)&xsf_lo, (void*)&enc_b, (void*)&c, (void*)&buf
    };
    hipLaunchCooperativeKernel((void*)enc_all, dim3(256), dim3(512), ea, 0,
                               stream);
  }
  // t=127 (odd) wrote hfA -> final h there

  dec_prep<<<NB, 256, 0, stream>>>(hfA_hi, hfA_lo, c, qA_hi, qA_lo);
  gemm_kp<<<dim3(302, 4), 256, 0, stream>>>(buf, Wqkf_hi, Wqkf_lo, kp);

  // decoder weight transforms (overwrite encoder overlays)
  frag_w4<<<4096, 256, 0, stream>>>(dec_Wih, 2048, 6, Wdxf_hi, Wdxf_lo, 1048576);
  frag_w4<<<2048, 256, 0, stream>>>(dec_Whh, 1024, 5, Wdhf_hi, Wdhf_lo, 524288);

  // Decoder: 24 steps x 3 phases, ONE cooperative launch
  {
    void* da[] = {
      (void*)&Xf_hi, (void*)&Xf_lo, (void*)&qA_hi, (void*)&qA_lo,
      (void*)&qB_hi, (void*)&qB_lo, (void*)&Wqkf_hi, (void*)&Wqkf_lo,
      (void*)&Wdxf_hi, (void*)&Wdxf_lo, (void*)&Wdhf_hi, (void*)&Wdhf_lo,
      (void*)&dec_b, (void*)&c, (void*)&buf, (void*)&kp, (void*)&qkout,
      (void*)&attn_Wv, (void*)&out_w, (void*)&out_b, (void*)&out
    };
    hipLaunchCooperativeKernel((void*)dec_all, dim3(256), dim3(512), da, 0,
                               stream);
  }
}

// Round 3
// 7411.107 us; speedup vs baseline: 1.3786x; 1.3786x over previous
//
#include <hip/hip_runtime.h>
#include <math.h>

// Round 12: flush-free fused encoder. r11 showed cg::grid.sync ~15-35us/sync
// (full L2 wb/inv across 8 non-coherent XCDs) -- WORSE than per-step launch
// (~21us). The actual cross-block data per step is tiny (h: 512KB), so:
// persistent enc_all (64 blocks x 512thr), h handoff via agent-scope RELAXED
// atomics (sc0sc1 -> LLC-coherent, bypasses per-XCD L2, NO flush), custom
// flag-array barrier (~1-2us). Wave = batch-tile (no A dup); weights stream
// from warm per-XCD L2. Decoder keeps r10 per-step 3-launch structure
// (known-good). Math identical to r10 (3-term hi/lo MFMA; single-chain K).

#define NB 128
#define NL 128
#define NH 1024
#define NA 256
#define NT 24
#define NM 151
#define ENCB 64

typedef __attribute__((ext_vector_type(8))) short bf16x8;
typedef __attribute__((ext_vector_type(8))) short s16x8;
typedef __attribute__((ext_vector_type(4))) float f32x4;

#define MFMA(a, b, acc) __builtin_amdgcn_mfma_f32_16x16x32_bf16(a, b, acc, 0, 0, 0)

#define I16_SCALE 32767.0f
#define I16_INV   (1.0f / 32767.0f)

__device__ __forceinline__ float sig_f(float x) {
  return 1.0f / (1.0f + __expf(-x));
}
__device__ __forceinline__ float tanh_f(float x) {
  x = fminf(9.0f, fmaxf(-9.0f, x));
  float e = __expf(2.0f * x);
  return (e - 1.0f) / (e + 1.0f);
}
__device__ __forceinline__ unsigned short f2bf(float f) {
  unsigned int u = __float_as_uint(f);
  u = (u + 0x7FFFu + ((u >> 16) & 1u)) >> 16;
  return (unsigned short)u;
}
__device__ __forceinline__ float bf2f(unsigned short u) {
  return __uint_as_float(((unsigned int)u) << 16);
}
__device__ __forceinline__ short f2i16(float f) {
  return (short)__float2int_rn(f * I16_SCALE);
}

// LLC-coherent (agent-scope, L2-bypassing) 16B load as two 8B atomic loads.
__device__ __forceinline__ bf16x8 ald16(const unsigned short* p) {
  unsigned long long a = __hip_atomic_load((const unsigned long long*)p,
      __ATOMIC_RELAXED, __HIP_MEMORY_SCOPE_AGENT);
  unsigned long long b = __hip_atomic_load((const unsigned long long*)(p + 4),
      __ATOMIC_RELAXED, __HIP_MEMORY_SCOPE_AGENT);
  union { unsigned long long u[2]; bf16x8 v; } x;
  x.u[0] = a; x.u[1] = b;
  return x.v;
}

// LLC-coherent 8B store of 4 packed ushorts.
__device__ __forceinline__ void ast8(unsigned short* p, unsigned short a,
                                     unsigned short b, unsigned short cc,
                                     unsigned short d) {
  unsigned long long u = (unsigned long long)a | ((unsigned long long)b << 16) |
                         ((unsigned long long)cc << 32) |
                         ((unsigned long long)d << 48);
  __hip_atomic_store((unsigned long long*)p, u, __ATOMIC_RELAXED,
                     __HIP_MEMORY_SCOPE_AGENT);
}

// Flush-free grid barrier: per-block flag (relaxed agent) + master poll +
// epoch broadcast. __syncthreads drains each wave's stores (vmcnt(0) before
// s_barrier) => flag implies the block's sc0sc1 data is LLC-visible.
__device__ __forceinline__ void gbar(unsigned int* bar, unsigned int ep) {
  __syncthreads();
  if (blockIdx.x == 0) {
    int tid = threadIdx.x;
    if (tid > 0 && tid < ENCB) {
      while (__hip_atomic_load(&bar[tid * 32], __ATOMIC_RELAXED,
                               __HIP_MEMORY_SCOPE_AGENT) < ep)
        __builtin_amdgcn_s_sleep(1);
    }
    __syncthreads();
    if (tid == 0)
      __hip_atomic_store(&bar[ENCB * 32], ep, __ATOMIC_RELAXED,
                         __HIP_MEMORY_SCOPE_AGENT);
  } else {
    if (threadIdx.x == 0) {
      __hip_atomic_store(&bar[blockIdx.x * 32], ep, __ATOMIC_RELAXED,
                         __HIP_MEMORY_SCOPE_AGENT);
      while (__hip_atomic_load(&bar[ENCB * 32], __ATOMIC_RELAXED,
                               __HIP_MEMORY_SCOPE_AGENT) < ep)
        __builtin_amdgcn_s_sleep(1);
    }
    __syncthreads();
  }
}

// ---------------------------------------------------------------------------
// conv front (proven round 1)
// ---------------------------------------------------------------------------
__global__ __launch_bounds__(128) void conv_front(
    const float* __restrict__ x,
    const float* __restrict__ w1, const float* __restrict__ b1,
    const float* __restrict__ w2, const float* __restrict__ b2,
    const float* __restrict__ w3, const float* __restrict__ b3,
    float* __restrict__ lstm_in)
{
  int b = blockIdx.x;
  int t = threadIdx.x;
  __shared__ float d[128][36];
  __shared__ float h1[128][34];
  __shared__ float h2[128][32];

  const float* xr = x + (size_t)(b * NL + t) * 48;
  #pragma unroll
  for (int f = 0; f < 36; ++f) d[t][f] = xr[f];
  __syncthreads();

  float acc[34];
  {
    float bias = b1[t];
    #pragma unroll
    for (int w = 0; w < 34; ++w) acc[w] = bias;
  }
  const float* wr = w1 + t * 384;
  for (int ci = 0; ci < 128; ++ci) {
    float row[36];
    #pragma unroll
    for (int f = 0; f < 36; ++f) row[f] = d[ci][f];
    float wa = wr[ci * 3 + 0], wb = wr[ci * 3 + 1], wc = wr[ci * 3 + 2];
    #pragma unroll
    for (int w = 0; w < 34; ++w)
      acc[w] += row[w] * wa + row[w + 1] * wb + row[w + 2] * wc;
  }
  #pragma unroll
  for (int w = 0; w < 34; ++w) {
    float z = acc[w];
    h1[t][w] = (z > 20.0f) ? z : log1pf(__expf(z));
  }
  __syncthreads();

  float acc2[32];
  {
    float bias = b2[t];
    #pragma unroll
    for (int w = 0; w < 32; ++w) acc2[w] = bias;
  }
  const float* wr2 = w2 + t * 384;
  for (int ci = 0; ci < 128; ++ci) {
    float row[34];
    #pragma unroll
    for (int f = 0; f < 34; ++f) row[f] = h1[ci][f];
    float wa = wr2[ci * 3 + 0], wb = wr2[ci * 3 + 1], wc = wr2[ci * 3 + 2];
    #pragma unroll
    for (int w = 0; w < 32; ++w)
      acc2[w] += row[w] * wa + row[w + 1] * wb + row[w + 2] * wc;
  }
  #pragma unroll
  for (int w = 0; w < 32; ++w) h2[t][w] = fmaxf(acc2[w], 0.0f);
  __syncthreads();

  float* outr = lstm_in + (size_t)(b * NL + t) * 18;
  #pragma unroll
  for (int e = 0; e < 6; ++e) {
    float s = b3[e];
    #pragma unroll
    for (int f = 0; f < 32; ++f) s += h2[t][f] * w3[e * 32 + f];
    outr[e] = s;
  }
  #pragma unroll
  for (int j = 0; j < 12; ++j) outr[6 + j] = xr[36 + j];
}

// ---------------------------------------------------------------------------
// Fragment-order transforms (4-column variant, as round 10).
// ---------------------------------------------------------------------------
__global__ void frag_w4(const float* __restrict__ src, int K, int kshift,
                        unsigned short* __restrict__ hi,
                        unsigned short* __restrict__ lo, int ngroups)
{
  int o = blockIdx.x * 256 + threadIdx.x;
  if (o >= ngroups) return;
  int lane = o & 63;
  int ki = (o >> 6) & ((1 << kshift) - 1);
  int t2 = o >> (6 + kshift);
  int l15 = lane & 15, q = lane >> 4;
  int grow = (l15 >> 2) * 1024 + t2 * 4 + (l15 & 3);
  const float* s = src + (size_t)grow * K + ki * 32 + q * 8;
  unsigned short hv[8], lv[8];
  #pragma unroll
  for (int j = 0; j < 8; ++j) {
    float v = s[j];
    hv[j] = f2bf(v);
    lv[j] = f2bf(v - bf2f(hv[j]));
  }
  size_t e = (size_t)o * 8;
  *(ushort4*)(hi + e) = make_ushort4(hv[0], hv[1], hv[2], hv[3]);
  *(ushort4*)(hi + e + 4) = make_ushort4(hv[4], hv[5], hv[6], hv[7]);
  *(ushort4*)(lo + e) = make_ushort4(lv[0], lv[1], lv[2], lv[3]);
  *(ushort4*)(lo + e + 4) = make_ushort4(lv[4], lv[5], lv[6], lv[7]);
}

__global__ void frag_wqk(const float* __restrict__ wq,
                         const float* __restrict__ wk,
                         unsigned short* __restrict__ hi,
                         unsigned short* __restrict__ lo)
{
  int o = blockIdx.x * 256 + threadIdx.x;
  if (o >= 65536) return;
  int lane = o & 63;
  int ki = (o >> 6) & 31;
  int ntile = o >> 11;
  int l15 = lane & 15, q = lane >> 4;
  int row = ntile * 16 + l15;
  int k = ki * 32 + q * 8;
  const float* s = (row < 256) ? (wq + (size_t)row * 1024 + k)
                               : (wk + (size_t)(row - 256) * 1024 + k);
  unsigned short hv[8], lv[8];
  #pragma unroll
  for (int j = 0; j < 8; ++j) {
    float v = s[j];
    hv[j] = f2bf(v);
    lv[j] = f2bf(v - bf2f(hv[j]));
  }
  size_t e = (size_t)o * 8;
  *(ushort4*)(hi + e) = make_ushort4(hv[0], hv[1], hv[2], hv[3]);
  *(ushort4*)(hi + e + 4) = make_ushort4(hv[4], hv[5], hv[6], hv[7]);
  *(ushort4*)(lo + e) = make_ushort4(lv[0], lv[1], lv[2], lv[3]);
  *(ushort4*)(lo + e + 4) = make_ushort4(lv[4], lv[5], lv[6], lv[7]);
}

__global__ void frag_wx4(const float* __restrict__ wih,
                         unsigned short* __restrict__ hi,
                         unsigned short* __restrict__ lo)
{
  int o = blockIdx.x * 256 + threadIdx.x;
  if (o >= 16384) return;
  int lane = o & 63;
  int t2 = o >> 6;
  int l15 = lane & 15, q = lane >> 4;
  int grow = (l15 >> 2) * 1024 + t2 * 4 + (l15 & 3);
  unsigned short hv[8], lv[8];
  #pragma unroll
  for (int j = 0; j < 8; ++j) {
    int k = q * 8 + j;
    float v = (k < 18) ? wih[(size_t)grow * 18 + k] : 0.0f;
    hv[j] = f2bf(v);
    lv[j] = f2bf(v - bf2f(hv[j]));
  }
  size_t e = (size_t)o * 8;
  *(ushort4*)(hi + e) = make_ushort4(hv[0], hv[1], hv[2], hv[3]);
  *(ushort4*)(hi + e + 4) = make_ushort4(hv[4], hv[5], hv[6], hv[7]);
  *(ushort4*)(lo + e) = make_ushort4(lv[0], lv[1], lv[2], lv[3]);
  *(ushort4*)(lo + e + 4) = make_ushort4(lv[4], lv[5], lv[6], lv[7]);
}

__global__ void frag_xs(const float* __restrict__ lstm_in,
                        unsigned short* __restrict__ hi,
                        unsigned short* __restrict__ lo)
{
  int o = blockIdx.x * 256 + threadIdx.x;
  if (o >= 65536) return;
  int lane = o & 63;
  int btile = (o >> 6) & 7;
  int t = o >> 9;
  int l15 = lane & 15, q = lane >> 4;
  int b = btile * 16 + l15;
  unsigned short hv[8], lv[8];
  #pragma unroll
  for (int j = 0; j < 8; ++j) {
    int k = q * 8 + j;
    float v = (k < 18) ? lstm_in[(size_t)(b * NL + t) * 18 + k] : 0.0f;
    hv[j] = f2bf(v);
    lv[j] = f2bf(v - bf2f(hv[j]));
  }
  size_t e = (size_t)o * 8;
  *(ushort4*)(hi + e) = make_ushort4(hv[0], hv[1], hv[2], hv[3]);
  *(ushort4*)(hi + e + 4) = make_ushort4(hv[4], hv[5], hv[6], hv[7]);
  *(ushort4*)(lo + e) = make_ushort4(lv[0], lv[1], lv[2], lv[3]);
  *(ushort4*)(lo + e + 4) = make_ushort4(lv[4], lv[5], lv[6], lv[7]);
}

__global__ void init_all(float* __restrict__ c,
                         unsigned short* __restrict__ hhi0,
                         unsigned short* __restrict__ hlo0,
                         float* __restrict__ out,
                         unsigned int* __restrict__ bar) {
  int i = blockIdx.x * 256 + threadIdx.x;
  if (i < NB * NH) { c[i] = 0.0f; hhi0[i] = 0; hlo0[i] = 0; }
  if (i < NB * NT) out[i] = 0.0f;
  if (i < ENCB * 32 + 32) bar[i] = 0;
}

// ---------------------------------------------------------------------------
// enc_all: all 128 encoder steps, persistent, 64 blocks x 512 thr.
// Block owns 16 gate-cols (t2 tiles 4bx..4bx+3). Wave w8 = batch-tile w8;
// each wave: 1 btile x 4 t2 x 32 ki x 3-term MFMA (A loaded once, W reused
// from warm L2). h handoff via agent-scope atomics; gbar between steps.
// ---------------------------------------------------------------------------
__global__ __launch_bounds__(512) void enc_all(
    unsigned short* __restrict__ hfA_hi, unsigned short* __restrict__ hfA_lo,
    unsigned short* __restrict__ hfB_hi, unsigned short* __restrict__ hfB_lo,
    const unsigned short* __restrict__ Wf_hi,
    const unsigned short* __restrict__ Wf_lo,
    const unsigned short* __restrict__ Wxf_hi,
    const unsigned short* __restrict__ Wxf_lo,
    const unsigned short* __restrict__ xsf_hi,
    const unsigned short* __restrict__ xsf_lo,
    const float* __restrict__ encb,
    float* __restrict__ c,
    short* __restrict__ buf,
    unsigned int* __restrict__ bar)
{
  __shared__ float G[4][128][17];
  int tid = threadIdx.x, bx = blockIdx.x;
  int w8 = tid >> 6, lane = tid & 63;
  int l15 = lane & 15, q4 = (lane >> 4) * 4;
  int ab = w8;                       // batch tile 0..7

  const unsigned short* B0h = Wf_hi + (size_t)(bx * 4) * 16384 + lane * 8;
  const unsigned short* B0l = Wf_lo + (size_t)(bx * 4) * 16384 + lane * 8;
  const unsigned short* X0h = Wxf_hi + (size_t)(bx * 4) * 512 + lane * 8;
  const unsigned short* X0l = Wxf_lo + (size_t)(bx * 4) * 512 + lane * 8;

  // epilogue mapping: 512 threads = 128 b x 4 colgrp
  int eb = tid & 127;
  int ecg = tid >> 7;
  int ekc = bx * 16 + ecg * 4;
  float bias[4][4];
  #pragma unroll
  for (int q = 0; q < 4; ++q)
    #pragma unroll
    for (int j = 0; j < 4; ++j)
      bias[q][j] = encb[q * NH + ekc + j];
  float4 creg = make_float4(0.f, 0.f, 0.f, 0.f);
  int eki = ekc >> 5, eqq = (ekc >> 3) & 3, ej8 = ekc & 7;
  size_t efo = (size_t)eki * 4096 + (eb >> 4) * 512 +
               ((eb & 15) + 16 * eqq) * 8 + ej8;

  for (int t = 0; t < NL; ++t) {
    const unsigned short* hih = (t & 1) ? hfB_hi : hfA_hi;
    const unsigned short* hil = (t & 1) ? hfB_lo : hfA_lo;
    unsigned short* hoh = (t & 1) ? hfA_hi : hfB_hi;
    unsigned short* hol = (t & 1) ? hfA_lo : hfB_lo;

    f32x4 a0 = {0,0,0,0}, a1 = {0,0,0,0}, a2 = {0,0,0,0}, a3 = {0,0,0,0};
    for (int ki = 0; ki < 32; ++ki) {
      size_t base = (size_t)ki * 4096 + ab * 512 + lane * 8;
      bf16x8 xh = ald16(hih + base);
      bf16x8 xl = ald16(hil + base);
      size_t bo = (size_t)ki * 512;
      bf16x8 y0h = *(const bf16x8*)(B0h + bo);
      bf16x8 y0l = *(const bf16x8*)(B0l + bo);
      bf16x8 y1h = *(const bf16x8*)(B0h + 16384 + bo);
      bf16x8 y1l = *(const bf16x8*)(B0l + 16384 + bo);
      bf16x8 y2h = *(const bf16x8*)(B0h + 32768 + bo);
      bf16x8 y2l = *(const bf16x8*)(B0l + 32768 + bo);
      bf16x8 y3h = *(const bf16x8*)(B0h + 49152 + bo);
      bf16x8 y3l = *(const bf16x8*)(B0l + 49152 + bo);
      a0 = MFMA(xh, y0h, a0); a0 = MFMA(xl, y0h, a0); a0 = MFMA(xh, y0l, a0);
      a1 = MFMA(xh, y1h, a1); a1 = MFMA(xl, y1h, a1); a1 = MFMA(xh, y1l, a1);
      a2 = MFMA(xh, y2h, a2); a2 = MFMA(xl, y2h, a2); a2 = MFMA(xh, y2l, a2);
      a3 = MFMA(xh, y3h, a3); a3 = MFMA(xl, y3h, a3); a3 = MFMA(xh, y3l, a3);
    }
    {
      size_t xo = ((size_t)t * 8 + ab) * 512 + lane * 8;
      bf16x8 xh = *(const bf16x8*)(xsf_hi + xo);
      bf16x8 xl = *(const bf16x8*)(xsf_lo + xo);
      bf16x8 y0h = *(const bf16x8*)X0h;
      bf16x8 y0l = *(const bf16x8*)X0l;
      bf16x8 y1h = *(const bf16x8*)(X0h + 512);
      bf16x8 y1l = *(const bf16x8*)(X0l + 512);
      bf16x8 y2h = *(const bf16x8*)(X0h + 1024);
      bf16x8 y2l = *(const bf16x8*)(X0l + 1024);
      bf16x8 y3h = *(const bf16x8*)(X0h + 1536);
      bf16x8 y3l = *(const bf16x8*)(X0l + 1536);
      a0 = MFMA(xh, y0h, a0); a0 = MFMA(xl, y0h, a0); a0 = MFMA(xh, y0l, a0);
      a1 = MFMA(xh, y1h, a1); a1 = MFMA(xl, y1h, a1); a1 = MFMA(xh, y1l, a1);
      a2 = MFMA(xh, y2h, a2); a2 = MFMA(xl, y2h, a2); a2 = MFMA(xh, y2l, a2);
      a3 = MFMA(xh, y3h, a3); a3 = MFMA(xl, y3h, a3); a3 = MFMA(xh, y3l, a3);
    }
    #pragma unroll
    for (int r = 0; r < 4; ++r) {
      G[0][ab * 16 + q4 + r][l15] = a0[r];
      G[1][ab * 16 + q4 + r][l15] = a1[r];
      G[2][ab * 16 + q4 + r][l15] = a2[r];
      G[3][ab * 16 + q4 + r][l15] = a3[r];
    }
    __syncthreads();

    // epilogue: all 512 threads, one (b, colgrp) each
    {
      float rh[4];
      float* cp = &creg.x;
      #pragma unroll
      for (int j = 0; j < 4; ++j) {
        float gate[4];
        #pragma unroll
        for (int q = 0; q < 4; ++q)
          gate[q] = G[ecg][eb][q * 4 + j] + bias[q][j];
        float cn = sig_f(gate[1]) * cp[j] + sig_f(gate[0]) * tanh_f(gate[2]);
        float hn = sig_f(gate[3]) * tanh_f(cn);
        cp[j] = cn; rh[j] = hn;
      }
      unsigned short hh[4], hl[4];
      short hq[4];
      #pragma unroll
      for (int j = 0; j < 4; ++j) {
        hh[j] = f2bf(rh[j]);
        hl[j] = f2bf(rh[j] - bf2f(hh[j]));
        hq[j] = f2i16(rh[j]);
      }
      ast8(hoh + efo, hh[0], hh[1], hh[2], hh[3]);
      ast8(hol + efo, hl[0], hl[1], hl[2], hl[3]);
      *(short4*)(buf + (size_t)(eb * NM + t) * NH + ekc) =
          make_short4(hq[0], hq[1], hq[2], hq[3]);
    }
    if (t < NL - 1) gbar(bar, (unsigned int)(t + 1));
  }
  *(float4*)(c + (size_t)eb * NH + ekc) = creg;
}

// ---------------------------------------------------------------------------
// dec_prep: read final h (frag) + c (row-major) -> q frag rows 2b / 2b+1.
// ---------------------------------------------------------------------------
__global__ __launch_bounds__(256) void dec_prep(
    const unsigned short* __restrict__ hf_hi,
    const unsigned short* __restrict__ hf_lo,
    const float* __restrict__ c,
    unsigned short* __restrict__ qhi, unsigned short* __restrict__ qlo)
{
  int b = blockIdx.x;
  int j4 = threadIdx.x * 4;
  int ki = j4 >> 5, qq = (j4 >> 3) & 3, j8 = j4 & 7;
  size_t fh = (size_t)ki * 4096 + (b >> 4) * 512 + ((b & 15) + 16 * qq) * 8 + j8;
  ushort4 hv = *(const ushort4*)(hf_hi + fh);
  ushort4 lv = *(const ushort4*)(hf_lo + fh);
  float4 cv = *(const float4*)(c + (size_t)b * NH + j4);
  unsigned short ch[4], cl[4];
  float cf[4] = {cv.x, cv.y, cv.z, cv.w};
  #pragma unroll
  for (int k = 0; k < 4; ++k) {
    ch[k] = f2bf(cf[k]); cl[k] = f2bf(cf[k] - bf2f(ch[k]));
  }
  int rt = (2 * b) >> 4;
  int rl = ((2 * b) & 15) + 16 * qq;
  size_t fq = (size_t)ki * 8192 + rt * 512 + rl * 8 + j8;
  *(ushort4*)(qhi + fq) = hv;
  *(ushort4*)(qlo + fq) = lv;
  *(ushort4*)(qhi + fq + 8) = make_ushort4(ch[0], ch[1], ch[2], ch[3]);
  *(ushort4*)(qlo + fq + 8) = make_ushort4(cl[0], cl[1], cl[2], cl[3]);
}

// ---------------------------------------------------------------------------
// gemm_qk (frag A + frag B): grid(16,16), 128 thr, wave per 16x16 tile.
// ---------------------------------------------------------------------------
__global__ __launch_bounds__(128) void gemm_qk(
    const unsigned short* __restrict__ Ahi, const unsigned short* __restrict__ Alo,
    const unsigned short* __restrict__ Bhi, const unsigned short* __restrict__ Blo,
    float* __restrict__ C)
{
  int tid = threadIdx.x;
  int w = tid >> 6, lane = tid & 63;
  int l15 = lane & 15, q4 = (lane >> 4) * 4;
  int mtile = blockIdx.x;
  int ntile = blockIdx.y * 2 + w;

  const unsigned short* Ah = Ahi + (size_t)mtile * 512 + lane * 8;
  const unsigned short* Al = Alo + (size_t)mtile * 512 + lane * 8;
  const unsigned short* Bh = Bhi + (size_t)ntile * 16384 + lane * 8;
  const unsigned short* Bl = Blo + (size_t)ntile * 16384 + lane * 8;
  f32x4 acc = {0, 0, 0, 0};
  for (int ki = 0; ki < 32; ++ki) {
    size_t ao = (size_t)ki * 8192;
    size_t bo = (size_t)ki * 512;
    bf16x8 ah = *(const bf16x8*)(Ah + ao);
    bf16x8 al = *(const bf16x8*)(Al + ao);
    bf16x8 bh = *(const bf16x8*)(Bh + bo);
    bf16x8 bl = *(const bf16x8*)(Bl + bo);
    acc = MFMA(ah, bh, acc);
    acc = MFMA(al, bh, acc);
    acc = MFMA(ah, bl, acc);
  }
  #pragma unroll
  for (int r = 0; r < 4; ++r)
    C[(size_t)(mtile * 16 + q4 + r) * 512 + ntile * 16 + l15] = acc[r];
}

// ---------------------------------------------------------------------------
// Bulk kp: kp = buf(i16, row-major) @ Wk^T (frag B, 2-term). grid(302,4).
// ---------------------------------------------------------------------------
__global__ __launch_bounds__(256) void gemm_kp(
    const short* __restrict__ A,
    const unsigned short* __restrict__ Bhi,
    const unsigned short* __restrict__ Blo,
    unsigned short* __restrict__ C)
{
  int tid = threadIdx.x;
  int w = tid >> 6, lane = tid & 63;
  int l15 = lane & 15, q8 = (lane >> 4) * 8, q4 = (lane >> 4) * 4;
  size_t m0 = (size_t)blockIdx.x * 64;
  int n0 = blockIdx.y * 64 + w * 16;
  int ntile = 16 + blockIdx.y * 4 + w;

  const unsigned short* Bh = Bhi + (size_t)ntile * 16384 + lane * 8;
  const unsigned short* Bl = Blo + (size_t)ntile * 16384 + lane * 8;
  f32x4 acc[4] = {{0,0,0,0},{0,0,0,0},{0,0,0,0},{0,0,0,0}};
  for (int ki = 0; ki < 32; ++ki) {
    int ko = ki * 32 + q8;
    size_t bo = (size_t)ki * 512;
    bf16x8 bh = *(const bf16x8*)(Bh + bo);
    bf16x8 bl = *(const bf16x8*)(Bl + bo);
    #pragma unroll
    for (int i = 0; i < 4; ++i) {
      s16x8 av = *(const s16x8*)(A + (m0 + 16 * i + l15) * (size_t)NH + ko);
      bf16x8 ah;
      #pragma unroll
      for (int k = 0; k < 8; ++k)
        ah[k] = (short)f2bf((float)av[k] * I16_INV);
      acc[i] = MFMA(ah, bh, acc[i]);
      acc[i] = MFMA(ah, bl, acc[i]);
    }
  }
  #pragma unroll
  for (int i = 0; i < 4; ++i)
    #pragma unroll
    for (int r = 0; r < 4; ++r)
      C[(m0 + 16 * i + q4 + r) * NA + n0 + l15] = f2bf(acc[i][r]);
}

// ---------------------------------------------------------------------------
// Attention: unchanged math; ctx written to Xc FRAG (A-layout, K=2048).
// ---------------------------------------------------------------------------
__global__ __launch_bounds__(256) void attn_kernel(
    const float* __restrict__ qkout,
    unsigned short* __restrict__ kp,
    const short* __restrict__ buf,
    const float* __restrict__ Wv,
    unsigned short* __restrict__ Xfhi,
    unsigned short* __restrict__ Xflo,
    int t)
{
  int b = blockIdx.x;
  int tid = threadIdx.x;
  int Mt = NL + t;
  __shared__ float sWv[256], q0[256], q1[256], kNew[256];
  __shared__ float sc[2][NM + 1];
  __shared__ float w0s[NM + 1], w1s[NM + 1];
  sWv[tid] = Wv[tid];
  q0[tid] = qkout[(size_t)(2 * b) * 512 + tid];
  q1[tid] = qkout[(size_t)(2 * b + 1) * 512 + tid];
  float kn = qkout[(size_t)(2 * b) * 512 + 256 + tid];
  kNew[tid] = kn;
  kp[((size_t)(b * NM) + (NL - 1 + t)) * NA + tid] = f2bf(kn);
  __syncthreads();

  for (int idx = tid; idx < 2 * Mt; idx += 256) {
    int m = idx >> 1, n = idx & 1;
    const float* q = n ? q1 : q0;
    float s = 0.0f;
    if (m == Mt - 1) {
      for (int a = 0; a < NA; ++a) s += tanh_f(q[a] + kNew[a]) * sWv[a];
    } else {
      const unsigned short* kpr = kp + ((size_t)(b * NM) + m) * NA;
      for (int a = 0; a < NA; a += 4) {
        ushort4 kv = *(const ushort4*)(kpr + a);
        s += tanh_f(q[a + 0] + bf2f(kv.x)) * sWv[a + 0];
        s += tanh_f(q[a + 1] + bf2f(kv.y)) * sWv[a + 1];
        s += tanh_f(q[a + 2] + bf2f(kv.z)) * sWv[a + 2];
        s += tanh_f(q[a + 3] + bf2f(kv.w)) * sWv[a + 3];
      }
    }
    sc[n][m] = s;
  }
  __syncthreads();
  for (int m = tid; m < Mt; m += 256) {
    float s0 = sc[0][m], s1 = sc[1][m];
    float mx = fmaxf(s0, s1);
    float e0 = __expf(s0 - mx), e1 = __expf(s1 - mx);
    float inv = 1.0f / (e0 + e1);
    w0s[m] = e0 * inv;
    w1s[m] = e1 * inv;
  }
  __syncthreads();

  float4 a0 = {0, 0, 0, 0}, a1 = {0, 0, 0, 0};
  const short* bb = buf + ((size_t)b * NM) * NH + tid * 4;
  for (int m = 0; m < Mt; ++m) {
    short4 v = *(const short4*)(bb + (size_t)m * NH);
    float vx = (float)v.x * I16_INV, vy = (float)v.y * I16_INV;
    float vz = (float)v.z * I16_INV, vw = (float)v.w * I16_INV;
    float w0 = w0s[m], w1 = w1s[m];
    a0.x += vx * w0; a0.y += vy * w0; a0.z += vz * w0; a0.w += vw * w0;
    a1.x += vx * w1; a1.y += vy * w1; a1.z += vz * w1; a1.w += vw * w1;
  }
  float v0[4] = {a0.x, a0.y, a0.z, a0.w};
  float v1[4] = {a1.x, a1.y, a1.z, a1.w};
  unsigned short h0[4], l0[4], h1v[4], l1v[4];
  #pragma unroll
  for (int k = 0; k < 4; ++k) {
    h0[k] = f2bf(v0[k]); l0[k] = f2bf(v0[k] - bf2f(h0[k]));
    h1v[k] = f2bf(v1[k]); l1v[k] = f2bf(v1[k] - bf2f(h1v[k]));
  }
  int k0 = tid * 4;
  size_t fo0 = (size_t)(k0 >> 5) * 4096 + (b >> 4) * 512 +
               ((b & 15) + 16 * ((k0 >> 3) & 3)) * 8 + (k0 & 7);
  int k1 = 1024 + tid * 4;
  size_t fo1 = (size_t)(k1 >> 5) * 4096 + (b >> 4) * 512 +
               ((b & 15) + 16 * ((k1 >> 3) & 3)) * 8 + (k1 & 7);
  *(ushort4*)(Xfhi + fo0) = make_ushort4(h0[0], h0[1], h0[2], h0[3]);
  *(ushort4*)(Xflo + fo0) = make_ushort4(l0[0], l0[1], l0[2], l0[3]);
  *(ushort4*)(Xfhi + fo1) = make_ushort4(h1v[0], h1v[1], h1v[2], h1v[3]);
  *(ushort4*)(Xflo + fo1) = make_ushort4(l1v[0], l1v[1], l1v[2], l1v[3]);
}

// ---------------------------------------------------------------------------
// Decoder step: 256 blocks x 512 thr, 4 gate-columns per block.
// ---------------------------------------------------------------------------
__global__ __launch_bounds__(512) void dec_step(
    const unsigned short* __restrict__ Xfhi,
    const unsigned short* __restrict__ Xflo,
    const unsigned short* __restrict__ qin_hi,
    const unsigned short* __restrict__ qin_lo,
    unsigned short* __restrict__ qout_hi,
    unsigned short* __restrict__ qout_lo,
    const unsigned short* __restrict__ Wdxf_hi,
    const unsigned short* __restrict__ Wdxf_lo,
    const unsigned short* __restrict__ Wdhf_hi,
    const unsigned short* __restrict__ Wdhf_lo,
    const float* __restrict__ decb,
    float* __restrict__ c,
    short* __restrict__ buf,
    const float* __restrict__ out_w, const float* __restrict__ out_b,
    float* __restrict__ out, int t)
{
  __shared__ float G[2][128][17];
  int tid = threadIdx.x;
  int w8 = tid >> 6, lane = tid & 63;
  int grp = w8 >> 2, wm = w8 & 3;
  int l15 = lane & 15, q4 = (lane >> 4) * 4;
  int bx = blockIdx.x;

  f32x4 a00 = {0,0,0,0}, a10 = {0,0,0,0};

  {
    const unsigned short* Wh = Wdxf_hi + (size_t)bx * 32768 + lane * 8;
    const unsigned short* Wl = Wdxf_lo + (size_t)bx * 32768 + lane * 8;
    const unsigned short* X0h = Xfhi + (size_t)(2 * wm) * 512 + lane * 8;
    const unsigned short* X1h = Xfhi + (size_t)(2 * wm + 1) * 512 + lane * 8;
    const unsigned short* X0l = Xflo + (size_t)(2 * wm) * 512 + lane * 8;
    const unsigned short* X1l = Xflo + (size_t)(2 * wm + 1) * 512 + lane * 8;
    int klo = grp ? 48 : 0;
    int khi = grp ? 64 : 48;
    for (int ki = klo; ki < khi; ++ki) {
      size_t ao = (size_t)ki * 4096;
      size_t bo = (size_t)ki * 512;
      bf16x8 x0h = *(const bf16x8*)(X0h + ao);
      bf16x8 x0l = *(const bf16x8*)(X0l + ao);
      bf16x8 x1h = *(const bf16x8*)(X1h + ao);
      bf16x8 x1l = *(const bf16x8*)(X1l + ao);
      bf16x8 yh = *(const bf16x8*)(Wh + bo);
      bf16x8 yl = *(const bf16x8*)(Wl + bo);
      a00 = MFMA(x0h, yh, a00); a00 = MFMA(x0l, yh, a00); a00 = MFMA(x0h, yl, a00);
      a10 = MFMA(x1h, yh, a10); a10 = MFMA(x1l, yh, a10); a10 = MFMA(x1h, yl, a10);
    }
  }
  if (grp) {
    int qt0 = 4 * wm + (l15 >> 3);
    int ln = 2 * (l15 & 7) + 16 * (lane >> 4);
    const unsigned short* A0h = qin_hi + (size_t)qt0 * 512 + ln * 8;
    const unsigned short* A0l = qin_lo + (size_t)qt0 * 512 + ln * 8;
    const unsigned short* A1h = qin_hi + (size_t)(qt0 + 2) * 512 + ln * 8;
    const unsigned short* A1l = qin_lo + (size_t)(qt0 + 2) * 512 + ln * 8;
    const unsigned short* Bh = Wdhf_hi + (size_t)bx * 16384 + lane * 8;
    const unsigned short* Bl = Wdhf_lo + (size_t)bx * 16384 + lane * 8;
    for (int ki = 0; ki < 32; ++ki) {
      size_t ao = (size_t)ki * 8192;
      size_t bo = (size_t)ki * 512;
      bf16x8 x0h = *(const bf16x8*)(A0h + ao);
      bf16x8 x0l = *(const bf16x8*)(A0l + ao);
      bf16x8 x1h = *(const bf16x8*)(A1h + ao);
      bf16x8 x1l = *(const bf16x8*)(A1l + ao);
      bf16x8 yh = *(const bf16x8*)(Bh + bo);
      bf16x8 yl = *(const bf16x8*)(Bl + bo);
      a00 = MFMA(x0h, yh, a00); a00 = MFMA(x0l, yh, a00); a00 = MFMA(x0h, yl, a00);
      a10 = MFMA(x1h, yh, a10); a10 = MFMA(x1l, yh, a10); a10 = MFMA(x1h, yl, a10);
    }
  }
  #pragma unroll
  for (int r = 0; r < 4; ++r) {
    G[grp][32 * wm + q4 + r][l15]      = a00[r];
    G[grp][32 * wm + 16 + q4 + r][l15] = a10[r];
  }
  __syncthreads();

  if (tid < 128) {
    int b = tid;
    int kc = bx * 4;
    float4 cold = *(const float4*)(c + (size_t)b * NH + kc);
    float rc[4], rh[4];
    #pragma unroll
    for (int j = 0; j < 4; ++j) {
      float gate[4];
      #pragma unroll
      for (int q = 0; q < 4; ++q) {
        int gi = q * 4 + j;
        gate[q] = G[0][b][gi] + G[1][b][gi] + decb[q * NH + kc + j];
      }
      float co = (&cold.x)[j];
      float cn = sig_f(gate[1]) * co + sig_f(gate[0]) * tanh_f(gate[2]);
      float hn = sig_f(gate[3]) * tanh_f(cn);
      rc[j] = cn; rh[j] = hn;
    }
    *(float4*)(c + (size_t)b * NH + kc) = make_float4(rc[0], rc[1], rc[2], rc[3]);

    float py = 0.0f;
    #pragma unroll
    for (int j = 0; j < 4; ++j) py += rh[j] * out_w[kc + j];
    if (bx == 0) py += out_b[0];
    atomicAdd(&out[b * NT + t], py);

    if (t < NT - 1) {
      unsigned short hh[4], hl[4], ch[4], cl[4];
      short hq[4];
      #pragma unroll
      for (int j = 0; j < 4; ++j) {
        hh[j] = f2bf(rh[j]); hl[j] = f2bf(rh[j] - bf2f(hh[j]));
        ch[j] = f2bf(rc[j]); cl[j] = f2bf(rc[j] - bf2f(ch[j]));
        hq[j] = f2i16(rh[j]);
      }
      *(short4*)(buf + (size_t)(b * NM + NL + t) * NH + kc) =
          make_short4(hq[0], hq[1], hq[2], hq[3]);
      int ki = kc >> 5, qq = (kc >> 3) & 3, j8 = kc & 7;
      int rt = (2 * b) >> 4;
      int rl = ((2 * b) & 15) + 16 * qq;
      size_t fq = (size_t)ki * 8192 + rt * 512 + rl * 8 + j8;
      *(ushort4*)(qout_hi + fq) = make_ushort4(hh[0], hh[1], hh[2], hh[3]);
      *(ushort4*)(qout_lo + fq) = make_ushort4(hl[0], hl[1], hl[2], hl[3]);
      *(ushort4*)(qout_hi + fq + 8) = make_ushort4(ch[0], ch[1], ch[2], ch[3]);
      *(ushort4*)(qout_lo + fq + 8) = make_ushort4(cl[0], cl[1], cl[2], cl[3]);
    }
  }
}

// ---------------------------------------------------------------------------
extern "C" void kernel_launch(void* const* d_in, const int* in_sizes, int n_in,
                              void* d_out, int out_size, void* d_ws, size_t ws_size,
                              hipStream_t stream) {
  const float* x       = (const float*)d_in[0];
  const float* conv1_w = (const float*)d_in[1];
  const float* conv1_b = (const float*)d_in[2];
  const float* conv2_w = (const float*)d_in[3];
  const float* conv2_b = (const float*)d_in[4];
  const float* lin3_w  = (const float*)d_in[5];
  const float* lin3_b  = (const float*)d_in[6];
  const float* enc_Wih = (const float*)d_in[7];
  const float* enc_Whh = (const float*)d_in[8];
  const float* enc_b   = (const float*)d_in[9];
  const float* attn_Wq = (const float*)d_in[10];
  const float* attn_Wk = (const float*)d_in[11];
  const float* attn_Wv = (const float*)d_in[12];
  const float* dec_Wih = (const float*)d_in[13];
  const float* dec_Whh = (const float*)d_in[14];
  const float* dec_b   = (const float*)d_in[15];
  const float* out_w   = (const float*)d_in[16];
  const float* out_b   = (const float*)d_in[17];
  float* out = (float*)d_out;

  // ---- workspace carve: identical totals to rounds 6-11 ----
  unsigned short* W = (unsigned short*)d_ws;
  short*          buf    = (short*)W;                  // 19,791,872 i16
  unsigned short* kp     = W + (size_t)19791872;       // 4,947,968
  unsigned short* qA_hi  = kp + 4947968;               // 262,144 (q frag)
  unsigned short* qA_lo  = qA_hi + 262144;
  unsigned short* qB_hi  = qA_lo + 262144;
  unsigned short* qB_lo  = qB_hi + 262144;
  unsigned short* Xf_hi  = qB_lo + 262144;             // 262,144 (ctx frag)
  unsigned short* Xf_lo  = Xf_hi + 262144;
  unsigned short* Wqkf_hi = Xf_lo + 262144;            // 524,288 (frag)
  unsigned short* Wqkf_lo = Wqkf_hi + 524288;
  unsigned short* Wdhf_hi = Wqkf_lo + 524288;          // 4,194,304 (enc Whh first)
  unsigned short* Wdhf_lo = Wdhf_hi + 4194304;
  unsigned short* Wdxf_hi = Wdhf_lo + 4194304;         // 8,388,608
  unsigned short* Wdxf_lo = Wdxf_hi + 8388608;         // 8,388,608
  float* c     = (float*)(Wdxf_lo + 8388608);          // 131,072 f
  float* qkout = c + 131072;                           // 131,072 f
  // encoder-phase overlays in Wdxf regions (dead until dec weight transform):
  unsigned short* hfA_hi = Wdxf_hi;                    // 131,072 (h frag)
  unsigned short* hfA_lo = Wdxf_hi + 131072;
  unsigned short* hfB_hi = Wdxf_hi + 262144;
  unsigned short* hfB_lo = Wdxf_hi + 393216;
  unsigned short* xsf_hi = Wdxf_hi + 524288;           // 524,288
  unsigned short* xsf_lo = xsf_hi + 524288;            // 524,288
  unsigned short* Wxf_hi = xsf_lo + 524288;            // 131,072
  unsigned short* Wxf_lo = Wxf_hi + 131072;            // 131,072
  float* lstm_in = (float*)Wdxf_lo;                    // 294,912 f
  // barrier state: dead space inside Wdxf_lo (past lstm_in, before region end)
  unsigned int* bar = (unsigned int*)(Wdxf_lo + 1048576);

  init_all<<<512, 256, 0, stream>>>(c, hfA_hi, hfA_lo, out, bar);
  conv_front<<<NB, 128, 0, stream>>>(x, conv1_w, conv1_b, conv2_w, conv2_b,
                                     lin3_w, lin3_b, lstm_in);
  frag_xs<<<256, 256, 0, stream>>>(lstm_in, xsf_hi, xsf_lo);
  frag_wx4<<<64, 256, 0, stream>>>(enc_Wih, Wxf_hi, Wxf_lo);
  frag_w4<<<2048, 256, 0, stream>>>(enc_Whh, 1024, 5, Wdhf_hi, Wdhf_lo, 524288);
  frag_wqk<<<256, 256, 0, stream>>>(attn_Wq, attn_Wk, Wqkf_hi, Wqkf_lo);

  // Encoder: 128 steps, ONE persistent launch with flush-free barrier
  {
    void* ea[] = {
      (void*)&hfA_hi, (void*)&hfA_lo, (void*)&hfB_hi, (void*)&hfB_lo,
      (void*)&Wdhf_hi, (void*)&Wdhf_lo, (void*)&Wxf_hi, (void*)&Wxf_lo,
      (void*)&xsf_hi, (void*)&xsf_lo, (void*)&enc_b, (void*)&c, (void*)&buf,
      (void*)&bar
    };
    hipLaunchCooperativeKernel((void*)enc_all, dim3(ENCB), dim3(512), ea, 0,
                               stream);
  }
  // t=127 (odd) wrote hfA -> final h there

  dec_prep<<<NB, 256, 0, stream>>>(hfA_hi, hfA_lo, c, qA_hi, qA_lo);
  gemm_kp<<<dim3(302, 4), 256, 0, stream>>>(buf, Wqkf_hi, Wqkf_lo, kp);

  // decoder weight transforms (overwrite encoder overlays)
  frag_w4<<<4096, 256, 0, stream>>>(dec_Wih, 2048, 6, Wdxf_hi, Wdxf_lo, 1048576);
  frag_w4<<<2048, 256, 0, stream>>>(dec_Whh, 1024, 5, Wdhf_hi, Wdhf_lo, 524288);

  for (int t = 0; t < NT; ++t) {
    const unsigned short* qih = (t & 1) ? qB_hi : qA_hi;
    const unsigned short* qil = (t & 1) ? qB_lo : qA_lo;
    unsigned short* qoh = (t & 1) ? qA_hi : qB_hi;
    unsigned short* qol = (t & 1) ? qA_lo : qB_lo;
    gemm_qk<<<dim3(16, 16), 128, 0, stream>>>(qih, qil, Wqkf_hi, Wqkf_lo, qkout);
    attn_kernel<<<NB, 256, 0, stream>>>(qkout, kp, buf, attn_Wv, Xf_hi, Xf_lo, t);
    dec_step<<<256, 512, 0, stream>>>(Xf_hi, Xf_lo, qih, qil, qoh, qol,
                                      Wdxf_hi, Wdxf_lo, Wdhf_hi, Wdhf_lo,
                                      dec_b, c, buf, out_w, out_b, out, t);
  }
}

// Round 4
// 4432.385 us; speedup vs baseline: 2.3050x; 1.6720x over previous
//
#include <hip/hip_runtime.h>
#include <math.h>

// Round 13: fix r12's latency-bound LLC handoff. r12: 34us/step, occupancy
// 6.2%, VALU 2.8% -- __hip_atomic_load h-reads are NOT pipelined by LLVM
// (serial ~600ns LLC round-trips). Fix: (1) h loads via inline-asm
// global_load_dwordx4 sc0 sc1 (plain pipelined LLC-coherent loads) with
// counted s_waitcnt vmcnt(12), 4-deep chunk pipeline, sched_barrier(0)
// after each wait (guide rule #18); (2) weights LDS-resident (128KB/block,
// staged once); (3) 128 blocks x 512thr x 8cols -- halves LLC traffic,
// wave = 1 btile x full K (no cross-wave K reduce); (4) atomicAdd barrier.
// Decoder unchanged (r10 per-step structure). Math identical (3-term hi/lo).

#define NB 128
#define NL 128
#define NH 1024
#define NA 256
#define NT 24
#define NM 151
#define ENCB 128

typedef __attribute__((ext_vector_type(8))) short bf16x8;
typedef __attribute__((ext_vector_type(8))) short s16x8;
typedef __attribute__((ext_vector_type(4))) float f32x4;

#define MFMA(a, b, acc) __builtin_amdgcn_mfma_f32_16x16x32_bf16(a, b, acc, 0, 0, 0)

#define I16_SCALE 32767.0f
#define I16_INV   (1.0f / 32767.0f)

__device__ __forceinline__ float sig_f(float x) {
  return 1.0f / (1.0f + __expf(-x));
}
__device__ __forceinline__ float tanh_f(float x) {
  x = fminf(9.0f, fmaxf(-9.0f, x));
  float e = __expf(2.0f * x);
  return (e - 1.0f) / (e + 1.0f);
}
__device__ __forceinline__ unsigned short f2bf(float f) {
  unsigned int u = __float_as_uint(f);
  u = (u + 0x7FFFu + ((u >> 16) & 1u)) >> 16;
  return (unsigned short)u;
}
__device__ __forceinline__ float bf2f(unsigned short u) {
  return __uint_as_float(((unsigned int)u) << 16);
}
__device__ __forceinline__ short f2i16(float f) {
  return (short)__float2int_rn(f * I16_SCALE);
}

// LLC-coherent 8B store of 4 packed ushorts (atomic relaxed agent: sc0sc1
// write-through; few per thread per step, serialization negligible).
__device__ __forceinline__ void ast8(unsigned short* p, unsigned short a,
                                     unsigned short b, unsigned short cc,
                                     unsigned short d) {
  unsigned long long u = (unsigned long long)a | ((unsigned long long)b << 16) |
                         ((unsigned long long)cc << 32) |
                         ((unsigned long long)d << 48);
  __hip_atomic_store((unsigned long long*)p, u, __ATOMIC_RELAXED,
                     __HIP_MEMORY_SCOPE_AGENT);
}

// Pipelined LLC-coherent 16B load: bypasses L1 (sc0) and L2 (sc1), hits LLC.
// NO implicit wait -- caller must s_waitcnt vmcnt(N) before use.
#define LLCLD(dst, ptr) \
  asm volatile("global_load_dwordx4 %0, %1, off sc0 sc1" \
               : "=v"(dst) : "v"(ptr))

#define WAITC(n)                                              \
  asm volatile("s_waitcnt vmcnt(" #n ")" ::: "memory");       \
  __builtin_amdgcn_sched_barrier(0)

// Flush-free grid barrier: one atomicAdd per block + poll (agent scope).
// __syncthreads first drains each wave's stores (vmcnt(0) before s_barrier)
// so counter==ENCB implies all blocks' sc0sc1 h-stores are LLC-visible.
__device__ __forceinline__ void gbar(unsigned int* bar, int t) {
  __syncthreads();
  if (threadIdx.x == 0) {
    unsigned int* cnt = bar + t * 32;
    __hip_atomic_fetch_add(cnt, 1u, __ATOMIC_RELAXED,
                           __HIP_MEMORY_SCOPE_AGENT);
    while (__hip_atomic_load(cnt, __ATOMIC_RELAXED,
                             __HIP_MEMORY_SCOPE_AGENT) < (unsigned)ENCB)
      __builtin_amdgcn_s_sleep(2);
  }
  __syncthreads();
}

// ---------------------------------------------------------------------------
// conv front (proven round 1)
// ---------------------------------------------------------------------------
__global__ __launch_bounds__(128) void conv_front(
    const float* __restrict__ x,
    const float* __restrict__ w1, const float* __restrict__ b1,
    const float* __restrict__ w2, const float* __restrict__ b2,
    const float* __restrict__ w3, const float* __restrict__ b3,
    float* __restrict__ lstm_in)
{
  int b = blockIdx.x;
  int t = threadIdx.x;
  __shared__ float d[128][36];
  __shared__ float h1[128][34];
  __shared__ float h2[128][32];

  const float* xr = x + (size_t)(b * NL + t) * 48;
  #pragma unroll
  for (int f = 0; f < 36; ++f) d[t][f] = xr[f];
  __syncthreads();

  float acc[34];
  {
    float bias = b1[t];
    #pragma unroll
    for (int w = 0; w < 34; ++w) acc[w] = bias;
  }
  const float* wr = w1 + t * 384;
  for (int ci = 0; ci < 128; ++ci) {
    float row[36];
    #pragma unroll
    for (int f = 0; f < 36; ++f) row[f] = d[ci][f];
    float wa = wr[ci * 3 + 0], wb = wr[ci * 3 + 1], wc = wr[ci * 3 + 2];
    #pragma unroll
    for (int w = 0; w < 34; ++w)
      acc[w] += row[w] * wa + row[w + 1] * wb + row[w + 2] * wc;
  }
  #pragma unroll
  for (int w = 0; w < 34; ++w) {
    float z = acc[w];
    h1[t][w] = (z > 20.0f) ? z : log1pf(__expf(z));
  }
  __syncthreads();

  float acc2[32];
  {
    float bias = b2[t];
    #pragma unroll
    for (int w = 0; w < 32; ++w) acc2[w] = bias;
  }
  const float* wr2 = w2 + t * 384;
  for (int ci = 0; ci < 128; ++ci) {
    float row[34];
    #pragma unroll
    for (int f = 0; f < 34; ++f) row[f] = h1[ci][f];
    float wa = wr2[ci * 3 + 0], wb = wr2[ci * 3 + 1], wc = wr2[ci * 3 + 2];
    #pragma unroll
    for (int w = 0; w < 32; ++w)
      acc2[w] += row[w] * wa + row[w + 1] * wb + row[w + 2] * wc;
  }
  #pragma unroll
  for (int w = 0; w < 32; ++w) h2[t][w] = fmaxf(acc2[w], 0.0f);
  __syncthreads();

  float* outr = lstm_in + (size_t)(b * NL + t) * 18;
  #pragma unroll
  for (int e = 0; e < 6; ++e) {
    float s = b3[e];
    #pragma unroll
    for (int f = 0; f < 32; ++f) s += h2[t][f] * w3[e * 32 + f];
    outr[e] = s;
  }
  #pragma unroll
  for (int j = 0; j < 12; ++j) outr[6 + j] = xr[36 + j];
}

// ---------------------------------------------------------------------------
// Fragment-order transforms (4-column variant, as round 10).
// ---------------------------------------------------------------------------
__global__ void frag_w4(const float* __restrict__ src, int K, int kshift,
                        unsigned short* __restrict__ hi,
                        unsigned short* __restrict__ lo, int ngroups)
{
  int o = blockIdx.x * 256 + threadIdx.x;
  if (o >= ngroups) return;
  int lane = o & 63;
  int ki = (o >> 6) & ((1 << kshift) - 1);
  int t2 = o >> (6 + kshift);
  int l15 = lane & 15, q = lane >> 4;
  int grow = (l15 >> 2) * 1024 + t2 * 4 + (l15 & 3);
  const float* s = src + (size_t)grow * K + ki * 32 + q * 8;
  unsigned short hv[8], lv[8];
  #pragma unroll
  for (int j = 0; j < 8; ++j) {
    float v = s[j];
    hv[j] = f2bf(v);
    lv[j] = f2bf(v - bf2f(hv[j]));
  }
  size_t e = (size_t)o * 8;
  *(ushort4*)(hi + e) = make_ushort4(hv[0], hv[1], hv[2], hv[3]);
  *(ushort4*)(hi + e + 4) = make_ushort4(hv[4], hv[5], hv[6], hv[7]);
  *(ushort4*)(lo + e) = make_ushort4(lv[0], lv[1], lv[2], lv[3]);
  *(ushort4*)(lo + e + 4) = make_ushort4(lv[4], lv[5], lv[6], lv[7]);
}

__global__ void frag_wqk(const float* __restrict__ wq,
                         const float* __restrict__ wk,
                         unsigned short* __restrict__ hi,
                         unsigned short* __restrict__ lo)
{
  int o = blockIdx.x * 256 + threadIdx.x;
  if (o >= 65536) return;
  int lane = o & 63;
  int ki = (o >> 6) & 31;
  int ntile = o >> 11;
  int l15 = lane & 15, q = lane >> 4;
  int row = ntile * 16 + l15;
  int k = ki * 32 + q * 8;
  const float* s = (row < 256) ? (wq + (size_t)row * 1024 + k)
                               : (wk + (size_t)(row - 256) * 1024 + k);
  unsigned short hv[8], lv[8];
  #pragma unroll
  for (int j = 0; j < 8; ++j) {
    float v = s[j];
    hv[j] = f2bf(v);
    lv[j] = f2bf(v - bf2f(hv[j]));
  }
  size_t e = (size_t)o * 8;
  *(ushort4*)(hi + e) = make_ushort4(hv[0], hv[1], hv[2], hv[3]);
  *(ushort4*)(hi + e + 4) = make_ushort4(hv[4], hv[5], hv[6], hv[7]);
  *(ushort4*)(lo + e) = make_ushort4(lv[0], lv[1], lv[2], lv[3]);
  *(ushort4*)(lo + e + 4) = make_ushort4(lv[4], lv[5], lv[6], lv[7]);
}

__global__ void frag_wx4(const float* __restrict__ wih,
                         unsigned short* __restrict__ hi,
                         unsigned short* __restrict__ lo)
{
  int o = blockIdx.x * 256 + threadIdx.x;
  if (o >= 16384) return;
  int lane = o & 63;
  int t2 = o >> 6;
  int l15 = lane & 15, q = lane >> 4;
  int grow = (l15 >> 2) * 1024 + t2 * 4 + (l15 & 3);
  unsigned short hv[8], lv[8];
  #pragma unroll
  for (int j = 0; j < 8; ++j) {
    int k = q * 8 + j;
    float v = (k < 18) ? wih[(size_t)grow * 18 + k] : 0.0f;
    hv[j] = f2bf(v);
    lv[j] = f2bf(v - bf2f(hv[j]));
  }
  size_t e = (size_t)o * 8;
  *(ushort4*)(hi + e) = make_ushort4(hv[0], hv[1], hv[2], hv[3]);
  *(ushort4*)(hi + e + 4) = make_ushort4(hv[4], hv[5], hv[6], hv[7]);
  *(ushort4*)(lo + e) = make_ushort4(lv[0], lv[1], lv[2], lv[3]);
  *(ushort4*)(lo + e + 4) = make_ushort4(lv[4], lv[5], lv[6], lv[7]);
}

__global__ void frag_xs(const float* __restrict__ lstm_in,
                        unsigned short* __restrict__ hi,
                        unsigned short* __restrict__ lo)
{
  int o = blockIdx.x * 256 + threadIdx.x;
  if (o >= 65536) return;
  int lane = o & 63;
  int btile = (o >> 6) & 7;
  int t = o >> 9;
  int l15 = lane & 15, q = lane >> 4;
  int b = btile * 16 + l15;
  unsigned short hv[8], lv[8];
  #pragma unroll
  for (int j = 0; j < 8; ++j) {
    int k = q * 8 + j;
    float v = (k < 18) ? lstm_in[(size_t)(b * NL + t) * 18 + k] : 0.0f;
    hv[j] = f2bf(v);
    lv[j] = f2bf(v - bf2f(hv[j]));
  }
  size_t e = (size_t)o * 8;
  *(ushort4*)(hi + e) = make_ushort4(hv[0], hv[1], hv[2], hv[3]);
  *(ushort4*)(hi + e + 4) = make_ushort4(hv[4], hv[5], hv[6], hv[7]);
  *(ushort4*)(lo + e) = make_ushort4(lv[0], lv[1], lv[2], lv[3]);
  *(ushort4*)(lo + e + 4) = make_ushort4(lv[4], lv[5], lv[6], lv[7]);
}

__global__ void init_all(float* __restrict__ c,
                         unsigned short* __restrict__ hhi0,
                         unsigned short* __restrict__ hlo0,
                         float* __restrict__ out,
                         unsigned int* __restrict__ bar) {
  int i = blockIdx.x * 256 + threadIdx.x;
  if (i < NB * NH) { c[i] = 0.0f; hhi0[i] = 0; hlo0[i] = 0; }
  if (i < NB * NT) out[i] = 0.0f;
  if (i < 8192) bar[i] = 0;
}

// ---------------------------------------------------------------------------
// enc_all v2: 128 blocks x 512 thr, 8 gate-cols per block (2 t2 tiles).
// Weights (128KB) + Wx (4KB) LDS-resident. Wave = 1 batch-tile x full K.
// h loads: asm sc0sc1 pipelined 4-deep (counted vmcnt). gbar between steps.
// ---------------------------------------------------------------------------
__global__ __launch_bounds__(512) void enc_all(
    unsigned short* __restrict__ hfA_hi, unsigned short* __restrict__ hfA_lo,
    unsigned short* __restrict__ hfB_hi, unsigned short* __restrict__ hfB_lo,
    const unsigned short* __restrict__ Wf_hi,
    const unsigned short* __restrict__ Wf_lo,
    const unsigned short* __restrict__ Wxf_hi,
    const unsigned short* __restrict__ Wxf_lo,
    const unsigned short* __restrict__ xsf_hi,
    const unsigned short* __restrict__ xsf_lo,
    const float* __restrict__ encb,
    float* __restrict__ c,
    short* __restrict__ buf,
    unsigned int* __restrict__ bar)
{
  __shared__ __align__(16) unsigned short SWh[32768];   // 2 tiles hi
  __shared__ __align__(16) unsigned short SWl[32768];   // 2 tiles lo
  __shared__ __align__(16) unsigned short SXh[1024];    // Wx 2 tiles hi
  __shared__ __align__(16) unsigned short SXl[1024];    // Wx 2 tiles lo
  __shared__ float G[128][33];

  int tid = threadIdx.x, bx = blockIdx.x;
  int w8 = tid >> 6, lane = tid & 63;
  int l15 = lane & 15, q4 = (lane >> 4) * 4;
  int ab = w8;                       // batch tile 0..7
  int lane8 = lane * 8;
  size_t abl8 = (size_t)ab * 512 + lane8;

  // stage weights to LDS (once, reused 128 steps)
  {
    const unsigned short* gh = Wf_hi + (size_t)(bx * 2) * 16384;
    const unsigned short* gl = Wf_lo + (size_t)(bx * 2) * 16384;
    for (int i = tid * 8; i < 32768; i += 4096) {
      *(bf16x8*)(SWh + i) = *(const bf16x8*)(gh + i);
      *(bf16x8*)(SWl + i) = *(const bf16x8*)(gl + i);
    }
    if (tid < 128) {
      *(bf16x8*)(SXh + tid * 8) =
          *(const bf16x8*)(Wxf_hi + (size_t)(bx * 2) * 512 + tid * 8);
      *(bf16x8*)(SXl + tid * 8) =
          *(const bf16x8*)(Wxf_lo + (size_t)(bx * 2) * 512 + tid * 8);
    }
  }

  // epilogue mapping: tid<256 -> (b, col-group lt)
  int eb = tid >> 1;
  int lt = tid & 1;
  int ekc = bx * 8 + lt * 4;
  float bias[4][4];
  #pragma unroll
  for (int q = 0; q < 4; ++q)
    #pragma unroll
    for (int j = 0; j < 4; ++j)
      bias[q][j] = encb[q * NH + ekc + j];
  float4 creg = make_float4(0.f, 0.f, 0.f, 0.f);
  int eki = ekc >> 5, eqq = (ekc >> 3) & 3, ej8 = ekc & 7;
  size_t efo = (size_t)eki * 4096 + (eb >> 4) * 512 +
               ((eb & 15) + 16 * eqq) * 8 + ej8;
  __syncthreads();

#define COMP1(kk) {                                                      \
    bf16x8 bh0 = *(const bf16x8*)(SWh + (kk) * 512 + lane8);             \
    bf16x8 bl0 = *(const bf16x8*)(SWl + (kk) * 512 + lane8);             \
    bf16x8 bh1 = *(const bf16x8*)(SWh + 16384 + (kk) * 512 + lane8);     \
    bf16x8 bl1 = *(const bf16x8*)(SWl + 16384 + (kk) * 512 + lane8);     \
    acc0 = MFMA(xh[kk], bh0, acc0); acc0 = MFMA(xl[kk], bh0, acc0);      \
    acc0 = MFMA(xh[kk], bl0, acc0);                                      \
    acc1 = MFMA(xh[kk], bh1, acc1); acc1 = MFMA(xl[kk], bh1, acc1);      \
    acc1 = MFMA(xh[kk], bl1, acc1); }

#define ISSUE(j) {                                                       \
    const unsigned short* p0 = hih + (size_t)(2 * (j)) * 4096 + abl8;    \
    const unsigned short* p1 = hil + (size_t)(2 * (j)) * 4096 + abl8;    \
    LLCLD(xh[2 * (j)], p0);                                              \
    LLCLD(xl[2 * (j)], p1);                                              \
    LLCLD(xh[2 * (j) + 1], p0 + 4096);                                   \
    LLCLD(xl[2 * (j) + 1], p1 + 4096); }

  for (int t = 0; t < NL; ++t) {
    const unsigned short* hih = (t & 1) ? hfB_hi : hfA_hi;
    const unsigned short* hil = (t & 1) ? hfB_lo : hfA_lo;
    unsigned short* hoh = (t & 1) ? hfA_hi : hfB_hi;
    unsigned short* hol = (t & 1) ? hfA_lo : hfB_lo;

    f32x4 acc0 = {0,0,0,0}, acc1 = {0,0,0,0};

    // xs term first (plain cached loads; compiler-managed waits)
    {
      size_t xo = ((size_t)t * 8 + ab) * 512 + lane8;
      bf16x8 sh = *(const bf16x8*)(xsf_hi + xo);
      bf16x8 sl = *(const bf16x8*)(xsf_lo + xo);
      bf16x8 y0h = *(const bf16x8*)(SXh + lane8);
      bf16x8 y0l = *(const bf16x8*)(SXl + lane8);
      bf16x8 y1h = *(const bf16x8*)(SXh + 512 + lane8);
      bf16x8 y1l = *(const bf16x8*)(SXl + 512 + lane8);
      acc0 = MFMA(sh, y0h, acc0); acc0 = MFMA(sl, y0h, acc0);
      acc0 = MFMA(sh, y0l, acc0);
      acc1 = MFMA(sh, y1h, acc1); acc1 = MFMA(sl, y1h, acc1);
      acc1 = MFMA(sh, y1l, acc1);
    }
    WAITC(0);   // drain compiler loads -> our vmcnt counts are exact

    bf16x8 xh[32], xl[32];
    ISSUE(0); ISSUE(1); ISSUE(2); ISSUE(3);
    WAITC(12); ISSUE(4);  COMP1(0);  COMP1(1);
    WAITC(12); ISSUE(5);  COMP1(2);  COMP1(3);
    WAITC(12); ISSUE(6);  COMP1(4);  COMP1(5);
    WAITC(12); ISSUE(7);  COMP1(6);  COMP1(7);
    WAITC(12); ISSUE(8);  COMP1(8);  COMP1(9);
    WAITC(12); ISSUE(9);  COMP1(10); COMP1(11);
    WAITC(12); ISSUE(10); COMP1(12); COMP1(13);
    WAITC(12); ISSUE(11); COMP1(14); COMP1(15);
    WAITC(12); ISSUE(12); COMP1(16); COMP1(17);
    WAITC(12); ISSUE(13); COMP1(18); COMP1(19);
    WAITC(12); ISSUE(14); COMP1(20); COMP1(21);
    WAITC(12); ISSUE(15); COMP1(22); COMP1(23);
    WAITC(12); COMP1(24); COMP1(25);
    WAITC(8);  COMP1(26); COMP1(27);
    WAITC(4);  COMP1(28); COMP1(29);
    WAITC(0);  COMP1(30); COMP1(31);

    #pragma unroll
    for (int r = 0; r < 4; ++r) {
      G[ab * 16 + q4 + r][l15]      = acc0[r];
      G[ab * 16 + q4 + r][16 + l15] = acc1[r];
    }
    __syncthreads();

    if (tid < 256) {
      float rh[4];
      float* cp = &creg.x;
      #pragma unroll
      for (int j = 0; j < 4; ++j) {
        float gate[4];
        #pragma unroll
        for (int q = 0; q < 4; ++q)
          gate[q] = G[eb][lt * 16 + q * 4 + j] + bias[q][j];
        float cn = sig_f(gate[1]) * cp[j] + sig_f(gate[0]) * tanh_f(gate[2]);
        float hn = sig_f(gate[3]) * tanh_f(cn);
        cp[j] = cn; rh[j] = hn;
      }
      unsigned short hh[4], hl[4];
      short hq[4];
      #pragma unroll
      for (int j = 0; j < 4; ++j) {
        hh[j] = f2bf(rh[j]);
        hl[j] = f2bf(rh[j] - bf2f(hh[j]));
        hq[j] = f2i16(rh[j]);
      }
      ast8(hoh + efo, hh[0], hh[1], hh[2], hh[3]);
      ast8(hol + efo, hl[0], hl[1], hl[2], hl[3]);
      *(short4*)(buf + (size_t)(eb * NM + t) * NH + ekc) =
          make_short4(hq[0], hq[1], hq[2], hq[3]);
    }
    if (t < NL - 1) gbar(bar, t);
  }
  if (tid < 256)
    *(float4*)(c + (size_t)eb * NH + ekc) = creg;
#undef COMP1
#undef ISSUE
}

// ---------------------------------------------------------------------------
// dec_prep: read final h (frag) + c (row-major) -> q frag rows 2b / 2b+1.
// ---------------------------------------------------------------------------
__global__ __launch_bounds__(256) void dec_prep(
    const unsigned short* __restrict__ hf_hi,
    const unsigned short* __restrict__ hf_lo,
    const float* __restrict__ c,
    unsigned short* __restrict__ qhi, unsigned short* __restrict__ qlo)
{
  int b = blockIdx.x;
  int j4 = threadIdx.x * 4;
  int ki = j4 >> 5, qq = (j4 >> 3) & 3, j8 = j4 & 7;
  size_t fh = (size_t)ki * 4096 + (b >> 4) * 512 + ((b & 15) + 16 * qq) * 8 + j8;
  ushort4 hv = *(const ushort4*)(hf_hi + fh);
  ushort4 lv = *(const ushort4*)(hf_lo + fh);
  float4 cv = *(const float4*)(c + (size_t)b * NH + j4);
  unsigned short ch[4], cl[4];
  float cf[4] = {cv.x, cv.y, cv.z, cv.w};
  #pragma unroll
  for (int k = 0; k < 4; ++k) {
    ch[k] = f2bf(cf[k]); cl[k] = f2bf(cf[k] - bf2f(ch[k]));
  }
  int rt = (2 * b) >> 4;
  int rl = ((2 * b) & 15) + 16 * qq;
  size_t fq = (size_t)ki * 8192 + rt * 512 + rl * 8 + j8;
  *(ushort4*)(qhi + fq) = hv;
  *(ushort4*)(qlo + fq) = lv;
  *(ushort4*)(qhi + fq + 8) = make_ushort4(ch[0], ch[1], ch[2], ch[3]);
  *(ushort4*)(qlo + fq + 8) = make_ushort4(cl[0], cl[1], cl[2], cl[3]);
}

// ---------------------------------------------------------------------------
// gemm_qk (frag A + frag B): grid(16,16), 128 thr, wave per 16x16 tile.
// ---------------------------------------------------------------------------
__global__ __launch_bounds__(128) void gemm_qk(
    const unsigned short* __restrict__ Ahi, const unsigned short* __restrict__ Alo,
    const unsigned short* __restrict__ Bhi, const unsigned short* __restrict__ Blo,
    float* __restrict__ C)
{
  int tid = threadIdx.x;
  int w = tid >> 6, lane = tid & 63;
  int l15 = lane & 15, q4 = (lane >> 4) * 4;
  int mtile = blockIdx.x;
  int ntile = blockIdx.y * 2 + w;

  const unsigned short* Ah = Ahi + (size_t)mtile * 512 + lane * 8;
  const unsigned short* Al = Alo + (size_t)mtile * 512 + lane * 8;
  const unsigned short* Bh = Bhi + (size_t)ntile * 16384 + lane * 8;
  const unsigned short* Bl = Blo + (size_t)ntile * 16384 + lane * 8;
  f32x4 acc = {0, 0, 0, 0};
  for (int ki = 0; ki < 32; ++ki) {
    size_t ao = (size_t)ki * 8192;
    size_t bo = (size_t)ki * 512;
    bf16x8 ah = *(const bf16x8*)(Ah + ao);
    bf16x8 al = *(const bf16x8*)(Al + ao);
    bf16x8 bh = *(const bf16x8*)(Bh + bo);
    bf16x8 bl = *(const bf16x8*)(Bl + bo);
    acc = MFMA(ah, bh, acc);
    acc = MFMA(al, bh, acc);
    acc = MFMA(ah, bl, acc);
  }
  #pragma unroll
  for (int r = 0; r < 4; ++r)
    C[(size_t)(mtile * 16 + q4 + r) * 512 + ntile * 16 + l15] = acc[r];
}

// ---------------------------------------------------------------------------
// Bulk kp: kp = buf(i16, row-major) @ Wk^T (frag B, 2-term). grid(302,4).
// ---------------------------------------------------------------------------
__global__ __launch_bounds__(256) void gemm_kp(
    const short* __restrict__ A,
    const unsigned short* __restrict__ Bhi,
    const unsigned short* __restrict__ Blo,
    unsigned short* __restrict__ C)
{
  int tid = threadIdx.x;
  int w = tid >> 6, lane = tid & 63;
  int l15 = lane & 15, q8 = (lane >> 4) * 8, q4 = (lane >> 4) * 4;
  size_t m0 = (size_t)blockIdx.x * 64;
  int n0 = blockIdx.y * 64 + w * 16;
  int ntile = 16 + blockIdx.y * 4 + w;

  const unsigned short* Bh = Bhi + (size_t)ntile * 16384 + lane * 8;
  const unsigned short* Bl = Blo + (size_t)ntile * 16384 + lane * 8;
  f32x4 acc[4] = {{0,0,0,0},{0,0,0,0},{0,0,0,0},{0,0,0,0}};
  for (int ki = 0; ki < 32; ++ki) {
    int ko = ki * 32 + q8;
    size_t bo = (size_t)ki * 512;
    bf16x8 bh = *(const bf16x8*)(Bh + bo);
    bf16x8 bl = *(const bf16x8*)(Bl + bo);
    #pragma unroll
    for (int i = 0; i < 4; ++i) {
      s16x8 av = *(const s16x8*)(A + (m0 + 16 * i + l15) * (size_t)NH + ko);
      bf16x8 ah;
      #pragma unroll
      for (int k = 0; k < 8; ++k)
        ah[k] = (short)f2bf((float)av[k] * I16_INV);
      acc[i] = MFMA(ah, bh, acc[i]);
      acc[i] = MFMA(ah, bl, acc[i]);
    }
  }
  #pragma unroll
  for (int i = 0; i < 4; ++i)
    #pragma unroll
    for (int r = 0; r < 4; ++r)
      C[(m0 + 16 * i + q4 + r) * NA + n0 + l15] = f2bf(acc[i][r]);
}

// ---------------------------------------------------------------------------
// Attention: unchanged math; ctx written to Xc FRAG (A-layout, K=2048).
// ---------------------------------------------------------------------------
__global__ __launch_bounds__(256) void attn_kernel(
    const float* __restrict__ qkout,
    unsigned short* __restrict__ kp,
    const short* __restrict__ buf,
    const float* __restrict__ Wv,
    unsigned short* __restrict__ Xfhi,
    unsigned short* __restrict__ Xflo,
    int t)
{
  int b = blockIdx.x;
  int tid = threadIdx.x;
  int Mt = NL + t;
  __shared__ float sWv[256], q0[256], q1[256], kNew[256];
  __shared__ float sc[2][NM + 1];
  __shared__ float w0s[NM + 1], w1s[NM + 1];
  sWv[tid] = Wv[tid];
  q0[tid] = qkout[(size_t)(2 * b) * 512 + tid];
  q1[tid] = qkout[(size_t)(2 * b + 1) * 512 + tid];
  float kn = qkout[(size_t)(2 * b) * 512 + 256 + tid];
  kNew[tid] = kn;
  kp[((size_t)(b * NM) + (NL - 1 + t)) * NA + tid] = f2bf(kn);
  __syncthreads();

  for (int idx = tid; idx < 2 * Mt; idx += 256) {
    int m = idx >> 1, n = idx & 1;
    const float* q = n ? q1 : q0;
    float s = 0.0f;
    if (m == Mt - 1) {
      for (int a = 0; a < NA; ++a) s += tanh_f(q[a] + kNew[a]) * sWv[a];
    } else {
      const unsigned short* kpr = kp + ((size_t)(b * NM) + m) * NA;
      for (int a = 0; a < NA; a += 4) {
        ushort4 kv = *(const ushort4*)(kpr + a);
        s += tanh_f(q[a + 0] + bf2f(kv.x)) * sWv[a + 0];
        s += tanh_f(q[a + 1] + bf2f(kv.y)) * sWv[a + 1];
        s += tanh_f(q[a + 2] + bf2f(kv.z)) * sWv[a + 2];
        s += tanh_f(q[a + 3] + bf2f(kv.w)) * sWv[a + 3];
      }
    }
    sc[n][m] = s;
  }
  __syncthreads();
  for (int m = tid; m < Mt; m += 256) {
    float s0 = sc[0][m], s1 = sc[1][m];
    float mx = fmaxf(s0, s1);
    float e0 = __expf(s0 - mx), e1 = __expf(s1 - mx);
    float inv = 1.0f / (e0 + e1);
    w0s[m] = e0 * inv;
    w1s[m] = e1 * inv;
  }
  __syncthreads();

  float4 a0 = {0, 0, 0, 0}, a1 = {0, 0, 0, 0};
  const short* bb = buf + ((size_t)b * NM) * NH + tid * 4;
  for (int m = 0; m < Mt; ++m) {
    short4 v = *(const short4*)(bb + (size_t)m * NH);
    float vx = (float)v.x * I16_INV, vy = (float)v.y * I16_INV;
    float vz = (float)v.z * I16_INV, vw = (float)v.w * I16_INV;
    float w0 = w0s[m], w1 = w1s[m];
    a0.x += vx * w0; a0.y += vy * w0; a0.z += vz * w0; a0.w += vw * w0;
    a1.x += vx * w1; a1.y += vy * w1; a1.z += vz * w1; a1.w += vw * w1;
  }
  float v0[4] = {a0.x, a0.y, a0.z, a0.w};
  float v1[4] = {a1.x, a1.y, a1.z, a1.w};
  unsigned short h0[4], l0[4], h1v[4], l1v[4];
  #pragma unroll
  for (int k = 0; k < 4; ++k) {
    h0[k] = f2bf(v0[k]); l0[k] = f2bf(v0[k] - bf2f(h0[k]));
    h1v[k] = f2bf(v1[k]); l1v[k] = f2bf(v1[k] - bf2f(h1v[k]));
  }
  int k0 = tid * 4;
  size_t fo0 = (size_t)(k0 >> 5) * 4096 + (b >> 4) * 512 +
               ((b & 15) + 16 * ((k0 >> 3) & 3)) * 8 + (k0 & 7);
  int k1 = 1024 + tid * 4;
  size_t fo1 = (size_t)(k1 >> 5) * 4096 + (b >> 4) * 512 +
               ((b & 15) + 16 * ((k1 >> 3) & 3)) * 8 + (k1 & 7);
  *(ushort4*)(Xfhi + fo0) = make_ushort4(h0[0], h0[1], h0[2], h0[3]);
  *(ushort4*)(Xflo + fo0) = make_ushort4(l0[0], l0[1], l0[2], l0[3]);
  *(ushort4*)(Xfhi + fo1) = make_ushort4(h1v[0], h1v[1], h1v[2], h1v[3]);
  *(ushort4*)(Xflo + fo1) = make_ushort4(l1v[0], l1v[1], l1v[2], l1v[3]);
}

// ---------------------------------------------------------------------------
// Decoder step: 256 blocks x 512 thr, 4 gate-columns per block.
// ---------------------------------------------------------------------------
__global__ __launch_bounds__(512) void dec_step(
    const unsigned short* __restrict__ Xfhi,
    const unsigned short* __restrict__ Xflo,
    const unsigned short* __restrict__ qin_hi,
    const unsigned short* __restrict__ qin_lo,
    unsigned short* __restrict__ qout_hi,
    unsigned short* __restrict__ qout_lo,
    const unsigned short* __restrict__ Wdxf_hi,
    const unsigned short* __restrict__ Wdxf_lo,
    const unsigned short* __restrict__ Wdhf_hi,
    const unsigned short* __restrict__ Wdhf_lo,
    const float* __restrict__ decb,
    float* __restrict__ c,
    short* __restrict__ buf,
    const float* __restrict__ out_w, const float* __restrict__ out_b,
    float* __restrict__ out, int t)
{
  __shared__ float G[2][128][17];
  int tid = threadIdx.x;
  int w8 = tid >> 6, lane = tid & 63;
  int grp = w8 >> 2, wm = w8 & 3;
  int l15 = lane & 15, q4 = (lane >> 4) * 4;
  int bx = blockIdx.x;

  f32x4 a00 = {0,0,0,0}, a10 = {0,0,0,0};

  {
    const unsigned short* Wh = Wdxf_hi + (size_t)bx * 32768 + lane * 8;
    const unsigned short* Wl = Wdxf_lo + (size_t)bx * 32768 + lane * 8;
    const unsigned short* X0h = Xfhi + (size_t)(2 * wm) * 512 + lane * 8;
    const unsigned short* X1h = Xfhi + (size_t)(2 * wm + 1) * 512 + lane * 8;
    const unsigned short* X0l = Xflo + (size_t)(2 * wm) * 512 + lane * 8;
    const unsigned short* X1l = Xflo + (size_t)(2 * wm + 1) * 512 + lane * 8;
    int klo = grp ? 48 : 0;
    int khi = grp ? 64 : 48;
    for (int ki = klo; ki < khi; ++ki) {
      size_t ao = (size_t)ki * 4096;
      size_t bo = (size_t)ki * 512;
      bf16x8 x0h = *(const bf16x8*)(X0h + ao);
      bf16x8 x0l = *(const bf16x8*)(X0l + ao);
      bf16x8 x1h = *(const bf16x8*)(X1h + ao);
      bf16x8 x1l = *(const bf16x8*)(X1l + ao);
      bf16x8 yh = *(const bf16x8*)(Wh + bo);
      bf16x8 yl = *(const bf16x8*)(Wl + bo);
      a00 = MFMA(x0h, yh, a00); a00 = MFMA(x0l, yh, a00); a00 = MFMA(x0h, yl, a00);
      a10 = MFMA(x1h, yh, a10); a10 = MFMA(x1l, yh, a10); a10 = MFMA(x1h, yl, a10);
    }
  }
  if (grp) {
    int qt0 = 4 * wm + (l15 >> 3);
    int ln = 2 * (l15 & 7) + 16 * (lane >> 4);
    const unsigned short* A0h = qin_hi + (size_t)qt0 * 512 + ln * 8;
    const unsigned short* A0l = qin_lo + (size_t)qt0 * 512 + ln * 8;
    const unsigned short* A1h = qin_hi + (size_t)(qt0 + 2) * 512 + ln * 8;
    const unsigned short* A1l = qin_lo + (size_t)(qt0 + 2) * 512 + ln * 8;
    const unsigned short* Bh = Wdhf_hi + (size_t)bx * 16384 + lane * 8;
    const unsigned short* Bl = Wdhf_lo + (size_t)bx * 16384 + lane * 8;
    for (int ki = 0; ki < 32; ++ki) {
      size_t ao = (size_t)ki * 8192;
      size_t bo = (size_t)ki * 512;
      bf16x8 x0h = *(const bf16x8*)(A0h + ao);
      bf16x8 x0l = *(const bf16x8*)(A0l + ao);
      bf16x8 x1h = *(const bf16x8*)(A1h + ao);
      bf16x8 x1l = *(const bf16x8*)(A1l + ao);
      bf16x8 yh = *(const bf16x8*)(Bh + bo);
      bf16x8 yl = *(const bf16x8*)(Bl + bo);
      a00 = MFMA(x0h, yh, a00); a00 = MFMA(x0l, yh, a00); a00 = MFMA(x0h, yl, a00);
      a10 = MFMA(x1h, yh, a10); a10 = MFMA(x1l, yh, a10); a10 = MFMA(x1h, yl, a10);
    }
  }
  #pragma unroll
  for (int r = 0; r < 4; ++r) {
    G[grp][32 * wm + q4 + r][l15]      = a00[r];
    G[grp][32 * wm + 16 + q4 + r][l15] = a10[r];
  }
  __syncthreads();

  if (tid < 128) {
    int b = tid;
    int kc = bx * 4;
    float4 cold = *(const float4*)(c + (size_t)b * NH + kc);
    float rc[4], rh[4];
    #pragma unroll
    for (int j = 0; j < 4; ++j) {
      float gate[4];
      #pragma unroll
      for (int q = 0; q < 4; ++q) {
        int gi = q * 4 + j;
        gate[q] = G[0][b][gi] + G[1][b][gi] + decb[q * NH + kc + j];
      }
      float co = (&cold.x)[j];
      float cn = sig_f(gate[1]) * co + sig_f(gate[0]) * tanh_f(gate[2]);
      float hn = sig_f(gate[3]) * tanh_f(cn);
      rc[j] = cn; rh[j] = hn;
    }
    *(float4*)(c + (size_t)b * NH + kc) = make_float4(rc[0], rc[1], rc[2], rc[3]);

    float py = 0.0f;
    #pragma unroll
    for (int j = 0; j < 4; ++j) py += rh[j] * out_w[kc + j];
    if (bx == 0) py += out_b[0];
    atomicAdd(&out[b * NT + t], py);

    if (t < NT - 1) {
      unsigned short hh[4], hl[4], ch[4], cl[4];
      short hq[4];
      #pragma unroll
      for (int j = 0; j < 4; ++j) {
        hh[j] = f2bf(rh[j]); hl[j] = f2bf(rh[j] - bf2f(hh[j]));
        ch[j] = f2bf(rc[j]); cl[j] = f2bf(rc[j] - bf2f(ch[j]));
        hq[j] = f2i16(rh[j]);
      }
      *(short4*)(buf + (size_t)(b * NM + NL + t) * NH + kc) =
          make_short4(hq[0], hq[1], hq[2], hq[3]);
      int ki = kc >> 5, qq = (kc >> 3) & 3, j8 = kc & 7;
      int rt = (2 * b) >> 4;
      int rl = ((2 * b) & 15) + 16 * qq;
      size_t fq = (size_t)ki * 8192 + rt * 512 + rl * 8 + j8;
      *(ushort4*)(qout_hi + fq) = make_ushort4(hh[0], hh[1], hh[2], hh[3]);
      *(ushort4*)(qout_lo + fq) = make_ushort4(hl[0], hl[1], hl[2], hl[3]);
      *(ushort4*)(qout_hi + fq + 8) = make_ushort4(ch[0], ch[1], ch[2], ch[3]);
      *(ushort4*)(qout_lo + fq + 8) = make_ushort4(cl[0], cl[1], cl[2], cl[3]);
    }
  }
}

// ---------------------------------------------------------------------------
extern "C" void kernel_launch(void* const* d_in, const int* in_sizes, int n_in,
                              void* d_out, int out_size, void* d_ws, size_t ws_size,
                              hipStream_t stream) {
  const float* x       = (const float*)d_in[0];
  const float* conv1_w = (const float*)d_in[1];
  const float* conv1_b = (const float*)d_in[2];
  const float* conv2_w = (const float*)d_in[3];
  const float* conv2_b = (const float*)d_in[4];
  const float* lin3_w  = (const float*)d_in[5];
  const float* lin3_b  = (const float*)d_in[6];
  const float* enc_Wih = (const float*)d_in[7];
  const float* enc_Whh = (const float*)d_in[8];
  const float* enc_b   = (const float*)d_in[9];
  const float* attn_Wq = (const float*)d_in[10];
  const float* attn_Wk = (const float*)d_in[11];
  const float* attn_Wv = (const float*)d_in[12];
  const float* dec_Wih = (const float*)d_in[13];
  const float* dec_Whh = (const float*)d_in[14];
  const float* dec_b   = (const float*)d_in[15];
  const float* out_w   = (const float*)d_in[16];
  const float* out_b   = (const float*)d_in[17];
  float* out = (float*)d_out;

  // ---- workspace carve: identical totals to rounds 6-12 ----
  unsigned short* W = (unsigned short*)d_ws;
  short*          buf    = (short*)W;                  // 19,791,872 i16
  unsigned short* kp     = W + (size_t)19791872;       // 4,947,968
  unsigned short* qA_hi  = kp + 4947968;               // 262,144 (q frag)
  unsigned short* qA_lo  = qA_hi + 262144;
  unsigned short* qB_hi  = qA_lo + 262144;
  unsigned short* qB_lo  = qB_hi + 262144;
  unsigned short* Xf_hi  = qB_lo + 262144;             // 262,144 (ctx frag)
  unsigned short* Xf_lo  = Xf_hi + 262144;
  unsigned short* Wqkf_hi = Xf_lo + 262144;            // 524,288 (frag)
  unsigned short* Wqkf_lo = Wqkf_hi + 524288;
  unsigned short* Wdhf_hi = Wqkf_lo + 524288;          // 4,194,304 (enc Whh first)
  unsigned short* Wdhf_lo = Wdhf_hi + 4194304;
  unsigned short* Wdxf_hi = Wdhf_lo + 4194304;         // 8,388,608
  unsigned short* Wdxf_lo = Wdxf_hi + 8388608;         // 8,388,608
  float* c     = (float*)(Wdxf_lo + 8388608);          // 131,072 f
  float* qkout = c + 131072;                           // 131,072 f
  // encoder-phase overlays in Wdxf regions (dead until dec weight transform):
  unsigned short* hfA_hi = Wdxf_hi;                    // 131,072 (h frag)
  unsigned short* hfA_lo = Wdxf_hi + 131072;
  unsigned short* hfB_hi = Wdxf_hi + 262144;
  unsigned short* hfB_lo = Wdxf_hi + 393216;
  unsigned short* xsf_hi = Wdxf_hi + 524288;           // 524,288
  unsigned short* xsf_lo = xsf_hi + 524288;            // 524,288
  unsigned short* Wxf_hi = xsf_lo + 524288;            // 131,072
  unsigned short* Wxf_lo = Wxf_hi + 131072;            // 131,072
  float* lstm_in = (float*)Wdxf_lo;                    // 294,912 f
  // barrier state: dead space inside Wdxf_lo (past lstm_in)
  unsigned int* bar = (unsigned int*)(Wdxf_lo + 1048576);

  init_all<<<512, 256, 0, stream>>>(c, hfA_hi, hfA_lo, out, bar);
  conv_front<<<NB, 128, 0, stream>>>(x, conv1_w, conv1_b, conv2_w, conv2_b,
                                     lin3_w, lin3_b, lstm_in);
  frag_xs<<<256, 256, 0, stream>>>(lstm_in, xsf_hi, xsf_lo);
  frag_wx4<<<64, 256, 0, stream>>>(enc_Wih, Wxf_hi, Wxf_lo);
  frag_w4<<<2048, 256, 0, stream>>>(enc_Whh, 1024, 5, Wdhf_hi, Wdhf_lo, 524288);
  frag_wqk<<<256, 256, 0, stream>>>(attn_Wq, attn_Wk, Wqkf_hi, Wqkf_lo);

  // Encoder: 128 steps, ONE persistent cooperative launch, flush-free barrier
  {
    void* ea[] = {
      (void*)&hfA_hi, (void*)&hfA_lo, (void*)&hfB_hi, (void*)&hfB_lo,
      (void*)&Wdhf_hi, (void*)&Wdhf_lo, (void*)&Wxf_hi, (void*)&Wxf_lo,
      (void*)&xsf_hi, (void*)&xsf_lo, (void*)&enc_b, (void*)&c, (void*)&buf,
      (void*)&bar
    };
    hipLaunchCooperativeKernel((void*)enc_all, dim3(ENCB), dim3(512), ea, 0,
                               stream);
  }
  // t=127 (odd) wrote hfA -> final h there

  dec_prep<<<NB, 256, 0, stream>>>(hfA_hi, hfA_lo, c, qA_hi, qA_lo);
  gemm_kp<<<dim3(302, 4), 256, 0, stream>>>(buf, Wqkf_hi, Wqkf_lo, kp);

  // decoder weight transforms (overwrite encoder overlays)
  frag_w4<<<4096, 256, 0, stream>>>(dec_Wih, 2048, 6, Wdxf_hi, Wdxf_lo, 1048576);
  frag_w4<<<2048, 256, 0, stream>>>(dec_Whh, 1024, 5, Wdhf_hi, Wdhf_lo, 524288);

  for (int t = 0; t < NT; ++t) {
    const unsigned short* qih = (t & 1) ? qB_hi : qA_hi;
    const unsigned short* qil = (t & 1) ? qB_lo : qA_lo;
    unsigned short* qoh = (t & 1) ? qA_hi : qB_hi;
    unsigned short* qol = (t & 1) ? qA_lo : qB_lo;
    gemm_qk<<<dim3(16, 16), 128, 0, stream>>>(qih, qil, Wqkf_hi, Wqkf_lo, qkout);
    attn_kernel<<<NB, 256, 0, stream>>>(qkout, kp, buf, attn_Wv, Xf_hi, Xf_lo, t);
    dec_step<<<256, 512, 0, stream>>>(Xf_hi, Xf_lo, qih, qil, qoh, qol,
                                      Wdxf_hi, Wdxf_lo, Wdhf_hi, Wdhf_lo,
                                      dec_b, c, buf, out_w, out_b, out, t);
  }
}